// Round 1
// baseline (650.844 us; speedup 1.0000x reference)
//
#include <hip/hip_runtime.h>

namespace {

constexpr int NBATCH = 4;
constexpr int NCH    = 256;   // C == HID
constexpr int NNODE  = 4096;  // 64*64
constexpr int TOPK   = 8;

// ---------- helpers ----------
__device__ __forceinline__ unsigned enc_f(float f) {
  unsigned u = __float_as_uint(f);
  return (u & 0x80000000u) ? ~u : (u | 0x80000000u);  // monotonic float->uint
}

// sorted-descending 8-element insert (keys pack (val asc-enc, ~idx))
__device__ __forceinline__ void ins8(unsigned long long* b, unsigned long long k) {
  if (k <= b[7]) return;
  b[7] = k;
#pragma unroll
  for (int p = 7; p >= 1; --p) {
    if (b[p] > b[p-1]) { unsigned long long t = b[p]; b[p] = b[p-1]; b[p-1] = t; }
  }
}

// ---------- 1. row-normalize batch-0 features: f0nT[c][n] ----------
__global__ __launch_bounds__(256) void norm_kernel(const float* __restrict__ feat,
                                                   float* __restrict__ f0nT) {
  int n = blockIdx.x * 256 + threadIdx.x;
  float ss = 0.f;
  for (int c = 0; c < NCH; ++c) { float v = feat[c*NNODE + n]; ss = fmaf(v, v, ss); }
  float inv = 1.f / fmaxf(sqrtf(ss), 1e-12f);
  for (int c = 0; c < NCH; ++c) f0nT[c*NNODE + n] = feat[c*NNODE + n] * inv;
}

// ---------- 2. sim panel GEMM: panel[r][j] = sum_c f0nT[c][m0+r]*f0nT[c][j] ----------
__global__ __launch_bounds__(256) void simgemm_kernel(const float* __restrict__ f0nT,
                                                      float* __restrict__ panel,
                                                      int m0base) {
  __shared__ float sa[64][132];
  __shared__ float sb[64][132];
  const int tid = threadIdx.x;
  const int tx = tid & 15, ty = tid >> 4;
  const int m0 = m0base + blockIdx.y * 128;
  const int j0 = blockIdx.x * 128;
  float acc[8][8];
#pragma unroll
  for (int i = 0; i < 8; ++i)
#pragma unroll
    for (int j = 0; j < 8; ++j) acc[i][j] = 0.f;

  for (int k0 = 0; k0 < NCH; k0 += 64) {
#pragma unroll
    for (int i = 0; i < 8; ++i) {
      int f4 = tid + i * 256;
      int kk = f4 >> 5, q = (f4 & 31) * 4;
      *(float4*)&sa[kk][q] = *(const float4*)&f0nT[(k0+kk)*NNODE + m0 + q];
      *(float4*)&sb[kk][q] = *(const float4*)&f0nT[(k0+kk)*NNODE + j0 + q];
    }
    __syncthreads();
#pragma unroll 8
    for (int k = 0; k < 64; ++k) {
      float av[8], bv[8];
      *(float4*)&av[0] = *(const float4*)&sa[k][ty*8];
      *(float4*)&av[4] = *(const float4*)&sa[k][ty*8+4];
      *(float4*)&bv[0] = *(const float4*)&sb[k][tx*8];
      *(float4*)&bv[4] = *(const float4*)&sb[k][tx*8+4];
#pragma unroll
      for (int i = 0; i < 8; ++i)
#pragma unroll
        for (int j = 0; j < 8; ++j) acc[i][j] = fmaf(av[i], bv[j], acc[i][j]);
    }
    __syncthreads();
  }
  int rbase = blockIdx.y * 128 + ty * 8;
#pragma unroll
  for (int i = 0; i < 8; ++i) {
    float* dst = panel + (size_t)(rbase + i) * NNODE + j0 + tx * 8;
#pragma unroll
    for (int j = 0; j < 8; j += 4) {
      *(float4*)(dst + j) = make_float4(acc[i][j], acc[i][j+1], acc[i][j+2], acc[i][j+3]);
    }
  }
}

// ---------- 3. exact top-8 per sim row (+ CSR degree counts) ----------
__global__ __launch_bounds__(256) void topk_kernel(const float* __restrict__ panel,
                                                   int rowbase,
                                                   int* __restrict__ idx8,
                                                   int* __restrict__ counts) {
  __shared__ unsigned long long L[256][8];
  int t = threadIdx.x;
  const float* srow = panel + (size_t)blockIdx.x * NNODE;
  unsigned long long b[8] = {0,0,0,0,0,0,0,0};
#pragma unroll
  for (int p = 0; p < 16; ++p) {
    int j = p * 256 + t;
    float v = srow[j];
    unsigned long long key =
        ((unsigned long long)enc_f(v) << 32) | (unsigned long long)(0xFFFFFFFFu - (unsigned)j);
    ins8(b, key);
  }
#pragma unroll
  for (int k = 0; k < 8; ++k) L[t][k] = b[k];
  __syncthreads();
  for (int s = 128; s >= 1; s >>= 1) {
    if (t < s) {
#pragma unroll
      for (int k = 0; k < 8; ++k) ins8(b, L[t+s][k]);
    }
    __syncthreads();
    if (t < s) {
#pragma unroll
      for (int k = 0; k < 8; ++k) L[t][k] = b[k];
    }
    __syncthreads();
  }
  if (t == 0) {
    int ig = rowbase + blockIdx.x;
#pragma unroll
    for (int k = 0; k < 8; ++k) {
      int j = (int)(0xFFFFFFFFu - (unsigned)(b[k] & 0xFFFFFFFFull));
      idx8[ig * 8 + k] = j;
      atomicAdd(&counts[j], 1);
    }
  }
}

// ---------- 4. CSR prefix scan (exclusive) + cursor init ----------
__global__ __launch_bounds__(256) void scan_kernel(const int* __restrict__ counts,
                                                   int* __restrict__ offsets,
                                                   int* __restrict__ cursor) {
  __shared__ int ssum[256];
  __shared__ int sbase[257];
  int t = threadIdx.x;
  int loc[16];
  int s = 0;
#pragma unroll
  for (int i = 0; i < 16; ++i) { loc[i] = s; s += counts[t*16 + i]; }
  ssum[t] = s;
  __syncthreads();
  if (t == 0) {
    int acc = 0;
    for (int i = 0; i < 256; ++i) { sbase[i] = acc; acc += ssum[i]; }
    sbase[256] = acc;
  }
  __syncthreads();
  int b0 = sbase[t];
#pragma unroll
  for (int i = 0; i < 16; ++i) {
    int off = b0 + loc[i];
    offsets[t*16 + i] = off;
    cursor [t*16 + i] = off;
  }
  if (t == 0) offsets[NNODE] = sbase[256];
}

// ---------- 5. CSR fill: node -> list of edges containing it ----------
__global__ __launch_bounds__(256) void fill_kernel(const int* __restrict__ idx8,
                                                   int* __restrict__ cursor,
                                                   int* __restrict__ edgelist) {
  int t = blockIdx.x * 256 + threadIdx.x;  // 32768 pairs
  int n = idx8[t];
  int pos = atomicAdd(&cursor[n], 1);
  edgelist[pos] = t >> 3;  // edge id
}

// ---------- 6. GEMM  out[m,o] = A[m,:]·W[:,o] + bias  (M=16384,K=256,O=256) ----------
// AMODE 0: A row-major [M,K]; AMODE 1: A = features [B][K=C][N] (k-major per batch)
template<int AMODE, int ACT>
__global__ __launch_bounds__(256) void gemm_xw_kernel(const float* __restrict__ A,
                                                      const float* __restrict__ W,
                                                      const float* __restrict__ bias,
                                                      float* __restrict__ out) {
  __shared__ float sa[64][132];
  __shared__ float sb[64][132];
  const int tid = threadIdx.x;
  const int tx = tid & 15, ty = tid >> 4;
  const int m0 = blockIdx.y * 128;
  const int o0 = blockIdx.x * 128;
  const float* Abase;
  if constexpr (AMODE == 1) {
    int bb = m0 >> 12;
    Abase = A + (size_t)bb * (NCH * NNODE) + (m0 & 4095);
  } else {
    Abase = A + (size_t)m0 * NCH;
  }
  float acc[8][8];
#pragma unroll
  for (int i = 0; i < 8; ++i)
#pragma unroll
    for (int j = 0; j < 8; ++j) acc[i][j] = 0.f;

  for (int k0 = 0; k0 < NCH; k0 += 64) {
    if constexpr (AMODE == 1) {
#pragma unroll
      for (int i = 0; i < 8; ++i) {
        int f4 = tid + i * 256;
        int kk = f4 >> 5, q = (f4 & 31) * 4;
        *(float4*)&sa[kk][q] = *(const float4*)&Abase[(size_t)(k0+kk)*NNODE + q];
      }
    } else {
#pragma unroll
      for (int i = 0; i < 8; ++i) {
        int f4 = tid + i * 256;
        int mm = f4 >> 4, k4 = (f4 & 15) * 4;
        float4 v = *(const float4*)&Abase[(size_t)mm*NCH + k0 + k4];
        sa[k4+0][mm] = v.x; sa[k4+1][mm] = v.y; sa[k4+2][mm] = v.z; sa[k4+3][mm] = v.w;
      }
    }
#pragma unroll
    for (int i = 0; i < 8; ++i) {
      int f4 = tid + i * 256;
      int kk = f4 >> 5, q = (f4 & 31) * 4;
      *(float4*)&sb[kk][q] = *(const float4*)&W[(size_t)(k0+kk)*NCH + o0 + q];
    }
    __syncthreads();
#pragma unroll 8
    for (int k = 0; k < 64; ++k) {
      float av[8], bv[8];
      *(float4*)&av[0] = *(const float4*)&sa[k][ty*8];
      *(float4*)&av[4] = *(const float4*)&sa[k][ty*8+4];
      *(float4*)&bv[0] = *(const float4*)&sb[k][tx*8];
      *(float4*)&bv[4] = *(const float4*)&sb[k][tx*8+4];
#pragma unroll
      for (int i = 0; i < 8; ++i)
#pragma unroll
        for (int j = 0; j < 8; ++j) acc[i][j] = fmaf(av[i], bv[j], acc[i][j]);
    }
    __syncthreads();
  }
#pragma unroll
  for (int i = 0; i < 8; ++i) {
    int m = m0 + ty * 8 + i;
    float* dst = out + (size_t)m * NCH + o0 + tx * 8;
#pragma unroll
    for (int jj = 0; jj < 8; jj += 4) {
      float4 v;
      v.x = acc[i][jj+0] + bias[o0+tx*8+jj+0];
      v.y = acc[i][jj+1] + bias[o0+tx*8+jj+1];
      v.z = acc[i][jj+2] + bias[o0+tx*8+jj+2];
      v.w = acc[i][jj+3] + bias[o0+tx*8+jj+3];
      if constexpr (ACT == 1) {
        v.x = fmaxf(v.x, 0.f); v.y = fmaxf(v.y, 0.f);
        v.z = fmaxf(v.z, 0.f); v.w = fmaxf(v.w, 0.f);
      }
      *(float4*)(dst + jj) = v;
    }
  }
}

// ---------- 7. edge gather: ef[b,e,:] = 1/8 sum_k xt[b, idx[e][k], :] ----------
__global__ __launch_bounds__(256) void gather_kernel(const float4* __restrict__ xt,
                                                     const int* __restrict__ idx8,
                                                     float4* __restrict__ ef) {
  int b = blockIdx.y;
  int e = blockIdx.x * 4 + (threadIdx.x >> 6);
  int lane = threadIdx.x & 63;
  float ax = 0, ay = 0, az = 0, aw = 0;
#pragma unroll
  for (int k = 0; k < TOPK; ++k) {
    int n = idx8[e * 8 + k];
    float4 v = xt[(size_t)((b << 12) + n) * 64 + lane];
    ax += v.x; ay += v.y; az += v.z; aw += v.w;
  }
  ef[(size_t)((b << 12) + e) * 64 + lane] =
      make_float4(ax * 0.125f, ay * 0.125f, az * 0.125f, aw * 0.125f);
}

// ---------- 8. node scatter: relu(1/8 sum_{e ∋ n} xp[b,e,:]) (+ residual) ----------
template<int MODE>  // 0: relu only; 1: relu + residual
__global__ __launch_bounds__(256) void scatter_kernel(const float4* __restrict__ xp,
                                                      const int* __restrict__ offsets,
                                                      const int* __restrict__ edgelist,
                                                      const float4* __restrict__ res,
                                                      float4* __restrict__ outb) {
  int b = blockIdx.y;
  int n = blockIdx.x * 4 + (threadIdx.x >> 6);
  int lane = threadIdx.x & 63;
  int s0 = offsets[n], s1 = offsets[n + 1];
  float ax = 0, ay = 0, az = 0, aw = 0;
  for (int j = s0; j < s1; ++j) {
    int e = edgelist[j];
    float4 v = xp[(size_t)((b << 12) + e) * 64 + lane];
    ax += v.x; ay += v.y; az += v.z; aw += v.w;
  }
  float4 r = make_float4(fmaxf(ax * 0.125f, 0.f), fmaxf(ay * 0.125f, 0.f),
                         fmaxf(az * 0.125f, 0.f), fmaxf(aw * 0.125f, 0.f));
  if constexpr (MODE == 1) {
    float4 v = res[(size_t)((b << 12) + n) * 64 + lane];
    r.x += v.x; r.y += v.y; r.z += v.z; r.w += v.w;
  }
  outb[(size_t)((b << 12) + n) * 64 + lane] = r;
}

// ---------- 9. BN batch statistics ----------
__global__ __launch_bounds__(256) void bnstats_kernel(const float* __restrict__ y,
                                                      float* __restrict__ bnsum) {
  int c = threadIdx.x;
  int r0 = blockIdx.x * 64;
  float s1 = 0.f, s2 = 0.f;
  for (int r = 0; r < 64; ++r) {
    float v = y[(size_t)(r0 + r) * NCH + c];
    s1 += v; s2 = fmaf(v, v, s2);
  }
  atomicAdd(&bnsum[c], s1);
  atomicAdd(&bnsum[NCH + c], s2);
}

__global__ __launch_bounds__(256) void bnfinal_kernel(const float* __restrict__ bnsum,
                                                      const float* __restrict__ gam,
                                                      const float* __restrict__ bet,
                                                      float* __restrict__ bnab) {
  int c = threadIdx.x;
  const float invn = 1.f / (float)(NBATCH * NNODE);
  float mean = bnsum[c] * invn;
  float var  = bnsum[NCH + c] * invn - mean * mean;
  float a = gam[c] * rsqrtf(var + 1e-5f);
  bnab[c] = a;
  bnab[NCH + c] = bet[c] - mean * a;
}

// ---------- 10. transpose + BN apply + residual with input features ----------
__global__ __launch_bounds__(256) void final_kernel(const float* __restrict__ y,
                                                    const float* __restrict__ feat,
                                                    const float* __restrict__ bnab,
                                                    float* __restrict__ out) {
  __shared__ float tile[64][65];
  int n0 = blockIdx.x * 64;
  int c0 = blockIdx.y * 64;
  int b  = blockIdx.z;
  int tid = threadIdx.x;
  int n_l = tid >> 2;   // 0..63
  int q   = tid & 3;    // 0..3
  const float4* y4 = (const float4*)y;
#pragma unroll
  for (int i = 0; i < 4; ++i) {
    int cl = q * 16 + i * 4;
    float4 v = y4[(size_t)(b * NNODE + n0 + n_l) * 64 + ((c0 + cl) >> 2)];
    tile[n_l][cl+0] = v.x; tile[n_l][cl+1] = v.y; tile[n_l][cl+2] = v.z; tile[n_l][cl+3] = v.w;
  }
  __syncthreads();
  int cl2 = tid >> 6;   // 0..3 (wave-uniform)
  int nl2 = tid & 63;
#pragma unroll
  for (int p = 0; p < 16; ++p) {
    int ci = p * 4 + cl2;
    int c = c0 + ci;
    float a = bnab[c], bb = bnab[NCH + c];
    size_t o = (size_t)b * (NCH * NNODE) + (size_t)c * NNODE + n0 + nl2;
    out[o] = feat[o] + fmaf(a, tile[nl2][ci], bb);
  }
}

}  // namespace

extern "C" void kernel_launch(void* const* d_in, const int* in_sizes, int n_in,
                              void* d_out, int out_size, void* d_ws, size_t ws_size,
                              hipStream_t stream) {
  (void)in_sizes; (void)n_in; (void)out_size; (void)ws_size;
  const float* feat = (const float*)d_in[0];
  const float* t0w  = (const float*)d_in[1];
  const float* t0b  = (const float*)d_in[2];
  const float* p0w  = (const float*)d_in[3];
  const float* p0b  = (const float*)d_in[4];
  const float* t1w  = (const float*)d_in[5];
  const float* t1b  = (const float*)d_in[6];
  const float* p1w  = (const float*)d_in[7];
  const float* p1b  = (const float*)d_in[8];
  const float* pw   = (const float*)d_in[9];
  const float* pb   = (const float*)d_in[10];
  const float* gam  = (const float*)d_in[11];
  const float* bet  = (const float*)d_in[12];
  float* out = (float*)d_out;

  // workspace layout (~68.3 MiB total)
  char* ws = (char*)d_ws;
  float* bufA = (float*)(ws);                       // 16 MiB (also sim panel)
  float* bufB = (float*)(ws + (16u << 20));         // 16 MiB
  float* bufC = (float*)(ws + (32u << 20));         // 16 MiB
  float* bufD = (float*)(ws + (48u << 20));         // 16 MiB
  float* f0nT = (float*)(ws + (64u << 20));         // 4 MiB
  char* small = ws + (68u << 20);
  int*   idx8     = (int*)(small);                  // 128 KiB
  int*   counts   = (int*)(small + 131072);         // 16 KiB
  int*   offsets  = (int*)(small + 147456);         // 16,388 B (padded)
  int*   cursor   = (int*)(small + 164096);         // 16 KiB
  int*   edgelist = (int*)(small + 180480);         // 128 KiB
  float* bnsum    = (float*)(small + 311552);       // 2 KiB
  float* bnab     = (float*)(small + 313600);       // 2 KiB

  hipMemsetAsync(counts, 0, NNODE * sizeof(int), stream);
  hipMemsetAsync(bnsum, 0, 2 * NCH * sizeof(float), stream);

  norm_kernel<<<NNODE / 256, 256, 0, stream>>>(feat, f0nT);

  // sim in 4 panels of 1024 rows (panel buffer aliases bufA, free until xt0)
  for (int p = 0; p < 4; ++p) {
    simgemm_kernel<<<dim3(32, 8), 256, 0, stream>>>(f0nT, bufA, p * 1024);
    topk_kernel<<<1024, 256, 0, stream>>>(bufA, p * 1024, idx8, counts);
  }
  scan_kernel<<<1, 256, 0, stream>>>(counts, offsets, cursor);
  fill_kernel<<<128, 256, 0, stream>>>(idx8, cursor, edgelist);

  // layer 0: xt0=theta0(feat) -> ef0 -> xp0=phi0 -> x1=relu(scatter)
  gemm_xw_kernel<1, 0><<<dim3(2, 128), 256, 0, stream>>>(feat, t0w, t0b, bufA);
  gather_kernel<<<dim3(1024, 4), 256, 0, stream>>>((const float4*)bufA, idx8, (float4*)bufB);
  gemm_xw_kernel<0, 0><<<dim3(2, 128), 256, 0, stream>>>(bufB, p0w, p0b, bufC);
  scatter_kernel<0><<<dim3(1024, 4), 256, 0, stream>>>((const float4*)bufC, offsets, edgelist,
                                                       nullptr, (float4*)bufD);
  // layer 1: xt1=theta1(x1) -> ef1 -> xp1=phi1 -> x2=relu(scatter)+x1
  gemm_xw_kernel<0, 0><<<dim3(2, 128), 256, 0, stream>>>(bufD, t1w, t1b, bufA);
  gather_kernel<<<dim3(1024, 4), 256, 0, stream>>>((const float4*)bufA, idx8, (float4*)bufB);
  gemm_xw_kernel<0, 0><<<dim3(2, 128), 256, 0, stream>>>(bufB, p1w, p1b, bufC);
  scatter_kernel<1><<<dim3(1024, 4), 256, 0, stream>>>((const float4*)bufC, offsets, edgelist,
                                                       (const float4*)bufD, (float4*)bufA);
  // proj -> y [B*N, C]
  gemm_xw_kernel<0, 0><<<dim3(2, 128), 256, 0, stream>>>(bufA, pw, pb, bufB);
  // BN stats + apply + residual (transposed back to [B,C,H,W])
  bnstats_kernel<<<256, 256, 0, stream>>>(bufB, bnsum);
  bnfinal_kernel<<<1, 256, 0, stream>>>(bnsum, gam, bet, bnab);
  final_kernel<<<dim3(64, 4, 4), 256, 0, stream>>>(bufB, feat, bnab, out);
}

// Round 3
// 439.346 us; speedup vs baseline: 1.4814x; 1.4814x over previous
//
#include <hip/hip_runtime.h>

namespace {

constexpr int NB = 4;
constexpr int NC = 256;   // C == HID
constexpr int NN = 4096;  // 64*64

typedef __attribute__((ext_vector_type(8))) short bf8;
typedef __attribute__((ext_vector_type(4))) float f4;

__device__ __forceinline__ float bf2f(unsigned short u) {
  return __uint_as_float(((unsigned)u) << 16);
}
__device__ __forceinline__ unsigned short f2bf(float f) {  // RNE
  unsigned x = __float_as_uint(f);
  return (unsigned short)((x + 0x7FFFu + ((x >> 16) & 1u)) >> 16);
}

__device__ __forceinline__ unsigned enc_f(float f) {
  unsigned u = __float_as_uint(f);
  return (u & 0x80000000u) ? ~u : (u | 0x80000000u);  // monotonic float->uint
}

// sorted-descending 8-element insert (keys pack (val asc-enc, ~idx))
__device__ __forceinline__ void ins8(unsigned long long* b, unsigned long long k) {
  if (k <= b[7]) return;
  b[7] = k;
#pragma unroll
  for (int p = 7; p >= 1; --p) {
    if (b[p] > b[p-1]) { unsigned long long t = b[p]; b[p] = b[p-1]; b[p-1] = t; }
  }
}

// ---------- 1. inverse row norms of batch-0 features ----------
__global__ __launch_bounds__(256) void norm_kernel(const float* __restrict__ feat,
                                                   float* __restrict__ inv) {
  int n = blockIdx.x * 256 + threadIdx.x;
  float ss = 0.f;
  for (int c = 0; c < NC; ++c) { float v = feat[(size_t)c * NN + n]; ss = fmaf(v, v, ss); }
  inv[n] = 1.f / fmaxf(sqrtf(ss), 1e-12f);
}

// ---------- 2. transpose + normalize + split: Xhi/Xlo [N][C] bf16 ----------
__global__ __launch_bounds__(256) void xpose_split_kernel(const float* __restrict__ feat,
                                                          const float* __restrict__ inv,
                                                          unsigned short* __restrict__ Xhi,
                                                          unsigned short* __restrict__ Xlo) {
  __shared__ float tile[64][65];
  int n0 = blockIdx.x * 64, c0 = blockIdx.y * 64;
  int tid = threadIdx.x;
#pragma unroll
  for (int i = 0; i < 4; ++i) {
    int u = tid + i * 256; int cr = u >> 4, q = u & 15;
    float4 v = *(const float4*)&feat[(size_t)(c0 + cr) * NN + n0 + q * 4];
    tile[cr][q*4+0] = v.x; tile[cr][q*4+1] = v.y; tile[cr][q*4+2] = v.z; tile[cr][q*4+3] = v.w;
  }
  __syncthreads();
#pragma unroll
  for (int i = 0; i < 4; ++i) {
    int u = tid + i * 256; int nr = u >> 4, q = u & 15;
    float iv = inv[n0 + nr];
    ushort4 h, l;
    float x0 = tile[q*4+0][nr] * iv, x1 = tile[q*4+1][nr] * iv;
    float x2 = tile[q*4+2][nr] * iv, x3 = tile[q*4+3][nr] * iv;
    h.x = f2bf(x0); l.x = f2bf(x0 - bf2f(h.x));
    h.y = f2bf(x1); l.y = f2bf(x1 - bf2f(h.y));
    h.z = f2bf(x2); l.z = f2bf(x2 - bf2f(h.z));
    h.w = f2bf(x3); l.w = f2bf(x3 - bf2f(h.w));
    size_t o = (size_t)(n0 + nr) * NC + c0 + q * 4;
    *(ushort4*)&Xhi[o] = h;
    *(ushort4*)&Xlo[o] = l;
  }
}

// ---------- 3. weight convert: W[k][n] fp32 -> Wt[n][k] bf16 (5 matrices) ----------
__global__ __launch_bounds__(256) void wcvt_kernel(const float* __restrict__ w0,
                                                   const float* __restrict__ w1,
                                                   const float* __restrict__ w2,
                                                   const float* __restrict__ w3,
                                                   const float* __restrict__ w4,
                                                   unsigned short* __restrict__ Wt) {
  __shared__ float tile[64][65];
  int z = blockIdx.z;
  const float* W = (z == 0) ? w0 : (z == 1) ? w1 : (z == 2) ? w2 : (z == 3) ? w3 : w4;
  int k0 = blockIdx.x * 64, n0 = blockIdx.y * 64;
  int tid = threadIdx.x;
#pragma unroll
  for (int i = 0; i < 4; ++i) {
    int u = tid + i * 256; int kr = u >> 4, q = u & 15;
    float4 v = *(const float4*)&W[(size_t)(k0 + kr) * NC + n0 + q * 4];
    tile[kr][q*4+0] = v.x; tile[kr][q*4+1] = v.y; tile[kr][q*4+2] = v.z; tile[kr][q*4+3] = v.w;
  }
  __syncthreads();
#pragma unroll
  for (int i = 0; i < 4; ++i) {
    int u = tid + i * 256; int nr = u >> 4, q = u & 15;
    ushort4 o;
    o.x = f2bf(tile[q*4+0][nr]); o.y = f2bf(tile[q*4+1][nr]);
    o.z = f2bf(tile[q*4+2][nr]); o.w = f2bf(tile[q*4+3][nr]);
    *(ushort4*)&Wt[(size_t)z * 65536 + (size_t)(n0 + nr) * NC + k0 + q * 4] = o;
  }
}

// ---------- 4. feat [B][C][N] -> xin [B*N][C] bf16 ----------
__global__ __launch_bounds__(256) void feat2bf_kernel(const float* __restrict__ feat,
                                                      unsigned short* __restrict__ xin) {
  __shared__ float tile[64][65];
  int n0 = blockIdx.x * 64, c0 = blockIdx.y * 64, b = blockIdx.z;
  int tid = threadIdx.x;
#pragma unroll
  for (int i = 0; i < 4; ++i) {
    int u = tid + i * 256; int cr = u >> 4, q = u & 15;
    float4 v = *(const float4*)&feat[((size_t)b * NC + c0 + cr) * NN + n0 + q * 4];
    tile[cr][q*4+0] = v.x; tile[cr][q*4+1] = v.y; tile[cr][q*4+2] = v.z; tile[cr][q*4+3] = v.w;
  }
  __syncthreads();
#pragma unroll
  for (int i = 0; i < 4; ++i) {
    int u = tid + i * 256; int nr = u >> 4, q = u & 15;
    ushort4 o;
    o.x = f2bf(tile[q*4+0][nr]); o.y = f2bf(tile[q*4+1][nr]);
    o.z = f2bf(tile[q*4+2][nr]); o.w = f2bf(tile[q*4+3][nr]);
    *(ushort4*)&xin[((size_t)(b << 12) + n0 + nr) * NC + c0 + q * 4] = o;
  }
}

// ---------- 5. sim panel via split-bf16 MFMA: panel[r][j], rows m0base.. ----------
__global__ __launch_bounds__(256) void simgemm_kernel(const unsigned short* __restrict__ Xhi,
                                                      const unsigned short* __restrict__ Xlo,
                                                      float* __restrict__ panel,
                                                      int m0base) {
  __shared__ unsigned short sAh[128][72];
  __shared__ unsigned short sAl[128][72];
  __shared__ unsigned short sBh[128][72];
  __shared__ unsigned short sBl[128][72];
  int tid = threadIdx.x, wave = tid >> 6, lane = tid & 63;
  int wm = wave >> 1, wn = wave & 1;
  int m0 = m0base + blockIdx.y * 128, n0 = blockIdx.x * 128;
  f4 acc[4][4];
#pragma unroll
  for (int i = 0; i < 4; ++i)
#pragma unroll
    for (int j = 0; j < 4; ++j) acc[i][j] = (f4){0.f, 0.f, 0.f, 0.f};

  for (int k0 = 0; k0 < NC; k0 += 64) {
#pragma unroll
    for (int i = 0; i < 4; ++i) {
      int u = tid + i * 256; int r = u >> 3, q = u & 7;
      size_t am = (size_t)(m0 + r) * NC + k0 + q * 8;
      size_t an = (size_t)(n0 + r) * NC + k0 + q * 8;
      *(uint4*)&sAh[r][q*8] = *(const uint4*)&Xhi[am];
      *(uint4*)&sAl[r][q*8] = *(const uint4*)&Xlo[am];
      *(uint4*)&sBh[r][q*8] = *(const uint4*)&Xhi[an];
      *(uint4*)&sBl[r][q*8] = *(const uint4*)&Xlo[an];
    }
    __syncthreads();
#pragma unroll
    for (int ks = 0; ks < 2; ++ks) {
      bf8 ah[4], al[4];
#pragma unroll
      for (int mf = 0; mf < 4; ++mf) {
        ah[mf] = *(const bf8*)&sAh[wm*64 + mf*16 + (lane & 15)][ks*32 + (lane >> 4)*8];
        al[mf] = *(const bf8*)&sAl[wm*64 + mf*16 + (lane & 15)][ks*32 + (lane >> 4)*8];
      }
#pragma unroll
      for (int nf = 0; nf < 4; ++nf) {
        bf8 bh = *(const bf8*)&sBh[wn*64 + nf*16 + (lane & 15)][ks*32 + (lane >> 4)*8];
        bf8 bl = *(const bf8*)&sBl[wn*64 + nf*16 + (lane & 15)][ks*32 + (lane >> 4)*8];
#pragma unroll
        for (int mf = 0; mf < 4; ++mf) {
          acc[mf][nf] = __builtin_amdgcn_mfma_f32_16x16x32_bf16(ah[mf], bh, acc[mf][nf], 0, 0, 0);
          acc[mf][nf] = __builtin_amdgcn_mfma_f32_16x16x32_bf16(ah[mf], bl, acc[mf][nf], 0, 0, 0);
          acc[mf][nf] = __builtin_amdgcn_mfma_f32_16x16x32_bf16(al[mf], bh, acc[mf][nf], 0, 0, 0);
        }
      }
    }
    __syncthreads();
  }
#pragma unroll
  for (int mf = 0; mf < 4; ++mf) {
#pragma unroll
    for (int nf = 0; nf < 4; ++nf) {
      int col = n0 + wn*64 + nf*16 + (lane & 15);
#pragma unroll
      for (int r = 0; r < 4; ++r) {
        int row = blockIdx.y * 128 + wm*64 + mf*16 + (lane >> 4)*4 + r;  // panel-local
        panel[(size_t)row * NN + col] = acc[mf][nf][r];
      }
    }
  }
}

// ---------- 6. exact top-8 per sim row (+ CSR degree counts) ----------
__global__ __launch_bounds__(256) void topk_kernel(const float* __restrict__ panel,
                                                   int rowbase,
                                                   int* __restrict__ idx8,
                                                   int* __restrict__ counts) {
  __shared__ unsigned long long L[256][8];
  int t = threadIdx.x;
  const float* srow = panel + (size_t)blockIdx.x * NN;
  unsigned long long b[8] = {0,0,0,0,0,0,0,0};
#pragma unroll
  for (int p = 0; p < 16; ++p) {
    int j = p * 256 + t;
    float v = srow[j];
    unsigned long long key =
        ((unsigned long long)enc_f(v) << 32) | (unsigned long long)(0xFFFFFFFFu - (unsigned)j);
    ins8(b, key);
  }
#pragma unroll
  for (int k = 0; k < 8; ++k) L[t][k] = b[k];
  __syncthreads();
  for (int s = 128; s >= 1; s >>= 1) {
    if (t < s) {
#pragma unroll
      for (int k = 0; k < 8; ++k) ins8(b, L[t+s][k]);
    }
    __syncthreads();
    if (t < s) {
#pragma unroll
      for (int k = 0; k < 8; ++k) L[t][k] = b[k];
    }
    __syncthreads();
  }
  if (t == 0) {
    int ig = rowbase + blockIdx.x;
#pragma unroll
    for (int k = 0; k < 8; ++k) {
      int j = (int)(0xFFFFFFFFu - (unsigned)(b[k] & 0xFFFFFFFFull));
      idx8[ig * 8 + k] = j;
      atomicAdd(&counts[j], 1);
    }
  }
}

// ---------- 7. CSR prefix scan (exclusive) + cursor init ----------
__global__ __launch_bounds__(256) void scan_kernel(const int* __restrict__ counts,
                                                   int* __restrict__ offsets,
                                                   int* __restrict__ cursor) {
  __shared__ int ssum[256];
  __shared__ int sbase[257];
  int t = threadIdx.x;
  int loc[16];
  int s = 0;
#pragma unroll
  for (int i = 0; i < 16; ++i) { loc[i] = s; s += counts[t*16 + i]; }
  ssum[t] = s;
  __syncthreads();
  if (t == 0) {
    int acc = 0;
    for (int i = 0; i < 256; ++i) { sbase[i] = acc; acc += ssum[i]; }
    sbase[256] = acc;
  }
  __syncthreads();
  int b0 = sbase[t];
#pragma unroll
  for (int i = 0; i < 16; ++i) {
    int off = b0 + loc[i];
    offsets[t*16 + i] = off;
    cursor [t*16 + i] = off;
  }
  if (t == 0) offsets[NN] = sbase[256];
}

// ---------- 8. CSR fill ----------
__global__ __launch_bounds__(256) void fill_kernel(const int* __restrict__ idx8,
                                                   int* __restrict__ cursor,
                                                   int* __restrict__ edgelist) {
  int t = blockIdx.x * 256 + threadIdx.x;  // 32768 pairs
  int n = idx8[t];
  int pos = atomicAdd(&cursor[n], 1);
  edgelist[pos] = t >> 3;
}

// ---------- 9. bf16 MFMA GEMM: out[m][n] = A[m][:]·Wt[n][:] + bias[n] ----------
template<int OUTF32>
__global__ __launch_bounds__(256) void gemm_bf16_kernel(const unsigned short* __restrict__ A,
                                                        const unsigned short* __restrict__ Wt,
                                                        const float* __restrict__ bias,
                                                        void* __restrict__ outp) {
  __shared__ unsigned short sA[64][72];
  __shared__ unsigned short sB[64][72];
  int tid = threadIdx.x, w = tid >> 6, lane = tid & 63;
  int m0 = blockIdx.y * 64, n0 = blockIdx.x * 64;
  f4 acc[4];
#pragma unroll
  for (int i = 0; i < 4; ++i) acc[i] = (f4){0.f, 0.f, 0.f, 0.f};

  for (int k0 = 0; k0 < NC; k0 += 64) {
#pragma unroll
    for (int i = 0; i < 2; ++i) {
      int u = tid + i * 256; int r = u >> 3, q = u & 7;
      *(uint4*)&sA[r][q*8] = *(const uint4*)&A [(size_t)(m0 + r) * NC + k0 + q * 8];
      *(uint4*)&sB[r][q*8] = *(const uint4*)&Wt[(size_t)(n0 + r) * NC + k0 + q * 8];
    }
    __syncthreads();
#pragma unroll
    for (int ks = 0; ks < 2; ++ks) {
      bf8 a = *(const bf8*)&sA[w*16 + (lane & 15)][ks*32 + (lane >> 4)*8];
#pragma unroll
      for (int nf = 0; nf < 4; ++nf) {
        bf8 bb = *(const bf8*)&sB[nf*16 + (lane & 15)][ks*32 + (lane >> 4)*8];
        acc[nf] = __builtin_amdgcn_mfma_f32_16x16x32_bf16(a, bb, acc[nf], 0, 0, 0);
      }
    }
    __syncthreads();
  }
#pragma unroll
  for (int nf = 0; nf < 4; ++nf) {
    int n = n0 + nf*16 + (lane & 15);
    float bi = bias[n];
#pragma unroll
    for (int r = 0; r < 4; ++r) {
      int m = m0 + w*16 + (lane >> 4)*4 + r;
      float v = acc[nf][r] + bi;
      if (OUTF32) ((float*)outp)[(size_t)m * NC + n] = v;
      else ((unsigned short*)outp)[(size_t)m * NC + n] = f2bf(v);
    }
  }
}

// ---------- 10. edge gather (bf16): ef[b,e,:] = 1/8 sum_k xt[b, idx[e][k], :] ----------
__global__ __launch_bounds__(256) void gather_kernel(const unsigned short* __restrict__ xt,
                                                     const int* __restrict__ idx8,
                                                     unsigned short* __restrict__ ef) {
  int b = blockIdx.y;
  int e = blockIdx.x * 4 + (threadIdx.x >> 6);
  int lane = threadIdx.x & 63;
  float s0 = 0, s1 = 0, s2 = 0, s3 = 0;
  const int* ip = &idx8[e * 8];
#pragma unroll
  for (int k = 0; k < 8; ++k) {
    int n = ip[k];
    uint2 v = *(const uint2*)&xt[((size_t)((b << 12) + n)) * NC + lane * 4];
    s0 += bf2f((unsigned short)(v.x & 0xFFFF)); s1 += bf2f((unsigned short)(v.x >> 16));
    s2 += bf2f((unsigned short)(v.y & 0xFFFF)); s3 += bf2f((unsigned short)(v.y >> 16));
  }
  uint2 o;
  o.x = (unsigned)f2bf(s0 * 0.125f) | ((unsigned)f2bf(s1 * 0.125f) << 16);
  o.y = (unsigned)f2bf(s2 * 0.125f) | ((unsigned)f2bf(s3 * 0.125f) << 16);
  *(uint2*)&ef[((size_t)((b << 12) + e)) * NC + lane * 4] = o;
}

// ---------- 11. node scatter (bf16): relu(1/8 sum_{e∋n} xp[b,e,:]) (+bf16 residual) ----------
template<int MODE>
__global__ __launch_bounds__(256) void scatter_kernel(const unsigned short* __restrict__ xp,
                                                      const int* __restrict__ offsets,
                                                      const int* __restrict__ edgelist,
                                                      const unsigned short* __restrict__ res,
                                                      unsigned short* __restrict__ outb) {
  int b = blockIdx.y;
  int n = blockIdx.x * 4 + (threadIdx.x >> 6);
  int lane = threadIdx.x & 63;
  int s0i = offsets[n], s1i = offsets[n + 1];
  float s0 = 0, s1 = 0, s2 = 0, s3 = 0;
  for (int j = s0i; j < s1i; ++j) {
    int e = edgelist[j];
    uint2 v = *(const uint2*)&xp[((size_t)((b << 12) + e)) * NC + lane * 4];
    s0 += bf2f((unsigned short)(v.x & 0xFFFF)); s1 += bf2f((unsigned short)(v.x >> 16));
    s2 += bf2f((unsigned short)(v.y & 0xFFFF)); s3 += bf2f((unsigned short)(v.y >> 16));
  }
  s0 = fmaxf(s0 * 0.125f, 0.f); s1 = fmaxf(s1 * 0.125f, 0.f);
  s2 = fmaxf(s2 * 0.125f, 0.f); s3 = fmaxf(s3 * 0.125f, 0.f);
  size_t o = ((size_t)((b << 12) + n)) * NC + lane * 4;
  if (MODE == 1) {
    uint2 v = *(const uint2*)&res[o];
    s0 += bf2f((unsigned short)(v.x & 0xFFFF)); s1 += bf2f((unsigned short)(v.x >> 16));
    s2 += bf2f((unsigned short)(v.y & 0xFFFF)); s3 += bf2f((unsigned short)(v.y >> 16));
  }
  uint2 ov;
  ov.x = (unsigned)f2bf(s0) | ((unsigned)f2bf(s1) << 16);
  ov.y = (unsigned)f2bf(s2) | ((unsigned)f2bf(s3) << 16);
  *(uint2*)&outb[o] = ov;
}

// ---------- 12. BN batch statistics ----------
__global__ __launch_bounds__(256) void bnstats_kernel(const float* __restrict__ y,
                                                      float* __restrict__ bnsum) {
  int c = threadIdx.x;
  int r0 = blockIdx.x * 64;
  float s1 = 0.f, s2 = 0.f;
  for (int r = 0; r < 64; ++r) {
    float v = y[(size_t)(r0 + r) * NC + c];
    s1 += v; s2 = fmaf(v, v, s2);
  }
  atomicAdd(&bnsum[c], s1);
  atomicAdd(&bnsum[NC + c], s2);
}

__global__ __launch_bounds__(256) void bnfinal_kernel(const float* __restrict__ bnsum,
                                                      const float* __restrict__ gam,
                                                      const float* __restrict__ bet,
                                                      float* __restrict__ bnab) {
  int c = threadIdx.x;
  const float invn = 1.f / (float)(NB * NN);
  float mean = bnsum[c] * invn;
  float var  = bnsum[NC + c] * invn - mean * mean;
  float a = gam[c] * rsqrtf(var + 1e-5f);
  bnab[c] = a;
  bnab[NC + c] = bet[c] - mean * a;
}

// ---------- 13. transpose + BN apply + residual with input features ----------
__global__ __launch_bounds__(256) void final_kernel(const float* __restrict__ y,
                                                    const float* __restrict__ feat,
                                                    const float* __restrict__ bnab,
                                                    float* __restrict__ out) {
  __shared__ float tile[64][65];
  int n0 = blockIdx.x * 64;
  int c0 = blockIdx.y * 64;
  int b  = blockIdx.z;
  int tid = threadIdx.x;
  int n_l = tid >> 2;
  int q   = tid & 3;
  const float4* y4 = (const float4*)y;
#pragma unroll
  for (int i = 0; i < 4; ++i) {
    int cl = q * 16 + i * 4;
    float4 v = y4[(size_t)(b * NN + n0 + n_l) * 64 + ((c0 + cl) >> 2)];
    tile[n_l][cl+0] = v.x; tile[n_l][cl+1] = v.y; tile[n_l][cl+2] = v.z; tile[n_l][cl+3] = v.w;
  }
  __syncthreads();
  int cl2 = tid >> 6;
  int nl2 = tid & 63;
#pragma unroll
  for (int p = 0; p < 16; ++p) {
    int ci = p * 4 + cl2;
    int c = c0 + ci;
    float a = bnab[c], bb = bnab[NC + c];
    size_t o = (size_t)b * (NC * NN) + (size_t)c * NN + n0 + nl2;
    out[o] = feat[o] + fmaf(a, tile[nl2][ci], bb);
  }
}

}  // namespace

extern "C" void kernel_launch(void* const* d_in, const int* in_sizes, int n_in,
                              void* d_out, int out_size, void* d_ws, size_t ws_size,
                              hipStream_t stream) {
  (void)in_sizes; (void)n_in; (void)out_size; (void)ws_size;
  const float* feat = (const float*)d_in[0];
  const float* t0w  = (const float*)d_in[1];
  const float* t0b  = (const float*)d_in[2];
  const float* p0w  = (const float*)d_in[3];
  const float* p0b  = (const float*)d_in[4];
  const float* t1w  = (const float*)d_in[5];
  const float* t1b  = (const float*)d_in[6];
  const float* p1w  = (const float*)d_in[7];
  const float* p1b  = (const float*)d_in[8];
  const float* pw   = (const float*)d_in[9];
  const float* pb   = (const float*)d_in[10];
  const float* gam  = (const float*)d_in[11];
  const float* bet  = (const float*)d_in[12];
  float* out = (float*)d_out;

  // workspace layout (~69 MiB)
  char* ws = (char*)d_ws;
  float*          panel = (float*)ws;                        // 16 MiB (panel; later y)
  float*          y     = (float*)ws;                        // aliases panel (dead by then)
  unsigned short* xin = (unsigned short*)(ws + (16u << 20)); // 8 MiB each
  unsigned short* xt  = (unsigned short*)(ws + (24u << 20));
  unsigned short* ef  = (unsigned short*)(ws + (32u << 20));
  unsigned short* xp  = (unsigned short*)(ws + (40u << 20));
  unsigned short* x1  = (unsigned short*)(ws + (48u << 20));
  unsigned short* x2  = (unsigned short*)(ws + (56u << 20));
  unsigned short* Xhi = (unsigned short*)(ws + (64u << 20)); // 2 MiB
  unsigned short* Xlo = (unsigned short*)(ws + (66u << 20)); // 2 MiB
  char* sm = ws + (68u << 20);
  unsigned short* Wt  = (unsigned short*)sm;                 // 5*128 KiB
  int*   idx8     = (int*)(sm + 655360);
  int*   counts   = (int*)(sm + 786432);
  int*   offsets  = (int*)(sm + 802816);
  int*   cursor   = (int*)(sm + 819456);
  int*   edgelist = (int*)(sm + 835840);
  float* inv      = (float*)(sm + 966912);
  float* bnsum    = (float*)(sm + 983296);
  float* bnab     = (float*)(sm + 985344);

  hipMemsetAsync(counts, 0, NN * sizeof(int), stream);
  hipMemsetAsync(bnsum, 0, 2 * NC * sizeof(float), stream);

  norm_kernel<<<NN / 256, 256, 0, stream>>>(feat, inv);
  xpose_split_kernel<<<dim3(64, 4), 256, 0, stream>>>(feat, inv, Xhi, Xlo);
  wcvt_kernel<<<dim3(4, 4, 5), 256, 0, stream>>>(t0w, p0w, t1w, p1w, pw, Wt);
  feat2bf_kernel<<<dim3(64, 4, 4), 256, 0, stream>>>(feat, xin);

  // sim in 4 panels of 1024 rows (panel buffer reused; freed before y)
  for (int p = 0; p < 4; ++p) {
    simgemm_kernel<<<dim3(32, 8), 256, 0, stream>>>(Xhi, Xlo, panel, p * 1024);
    topk_kernel<<<1024, 256, 0, stream>>>(panel, p * 1024, idx8, counts);
  }
  scan_kernel<<<1, 256, 0, stream>>>(counts, offsets, cursor);
  fill_kernel<<<128, 256, 0, stream>>>(idx8, cursor, edgelist);

  // layer 0
  gemm_bf16_kernel<0><<<dim3(4, 256), 256, 0, stream>>>(xin, Wt + 0*65536, t0b, xt);
  gather_kernel<<<dim3(1024, 4), 256, 0, stream>>>(xt, idx8, ef);
  gemm_bf16_kernel<0><<<dim3(4, 256), 256, 0, stream>>>(ef, Wt + 1*65536, p0b, xp);
  scatter_kernel<0><<<dim3(1024, 4), 256, 0, stream>>>(xp, offsets, edgelist, nullptr, x1);
  // layer 1
  gemm_bf16_kernel<0><<<dim3(4, 256), 256, 0, stream>>>(x1, Wt + 2*65536, t1b, xt);
  gather_kernel<<<dim3(1024, 4), 256, 0, stream>>>(xt, idx8, ef);
  gemm_bf16_kernel<0><<<dim3(4, 256), 256, 0, stream>>>(ef, Wt + 3*65536, p1b, xp);
  scatter_kernel<1><<<dim3(1024, 4), 256, 0, stream>>>(xp, offsets, edgelist, x1, x2);
  // proj (fp32 out for BN)
  gemm_bf16_kernel<1><<<dim3(4, 256), 256, 0, stream>>>(x2, Wt + 4*65536, pb, y);

  bnstats_kernel<<<256, 256, 0, stream>>>(y, bnsum);
  bnfinal_kernel<<<1, 256, 0, stream>>>(bnsum, gam, bet, bnab);
  final_kernel<<<dim3(64, 4, 4), 256, 0, stream>>>(y, feat, bnab, out);
}

// Round 4
// 369.494 us; speedup vs baseline: 1.7614x; 1.1890x over previous
//
#include <hip/hip_runtime.h>

namespace {

constexpr int NB = 4;
constexpr int NC = 256;   // C == HID
constexpr int NN = 4096;  // 64*64

typedef __attribute__((ext_vector_type(8))) short bf8;
typedef __attribute__((ext_vector_type(4))) float f4;
typedef unsigned short ushort_t;
typedef unsigned long long ull;

__device__ __forceinline__ float bf2f(unsigned short u) {
  return __uint_as_float(((unsigned)u) << 16);
}
__device__ __forceinline__ unsigned short f2bf(float f) {  // RNE
  unsigned x = __float_as_uint(f);
  return (unsigned short)((x + 0x7FFFu + ((x >> 16) & 1u)) >> 16);
}

__device__ __forceinline__ unsigned enc_f(float f) {
  unsigned u = __float_as_uint(f);
  return (u & 0x80000000u) ? ~u : (u | 0x80000000u);  // monotonic float->uint
}

// sorted-descending 8-element insert (keys pack (val asc-enc, ~idx))
__device__ __forceinline__ void ins8(ull* b, ull k) {
  if (k <= b[7]) return;
  b[7] = k;
#pragma unroll
  for (int p = 7; p >= 1; --p) {
    if (b[p] > b[p-1]) { ull t = b[p]; b[p] = b[p-1]; b[p-1] = t; }
  }
}

// ---------- 1. inverse row norms of batch-0 features (+ zero counts/bnsum) ----------
__global__ __launch_bounds__(256) void norm_kernel(const float* __restrict__ feat,
                                                   float* __restrict__ inv,
                                                   int* __restrict__ counts,
                                                   float* __restrict__ bnsum) {
  int n = blockIdx.x * 256 + threadIdx.x;
  counts[n] = 0;
  if (n < 2 * NC) bnsum[n] = 0.f;
  float ss = 0.f;
  for (int c = 0; c < NC; ++c) { float v = feat[(size_t)c * NN + n]; ss = fmaf(v, v, ss); }
  inv[n] = 1.f / fmaxf(sqrtf(ss), 1e-12f);
}

// ---------- 2. transpose + normalize + split: Xhi/Xlo [N][C] bf16 ----------
__global__ __launch_bounds__(256) void xpose_split_kernel(const float* __restrict__ feat,
                                                          const float* __restrict__ inv,
                                                          unsigned short* __restrict__ Xhi,
                                                          unsigned short* __restrict__ Xlo) {
  __shared__ float tile[64][65];
  int n0 = blockIdx.x * 64, c0 = blockIdx.y * 64;
  int tid = threadIdx.x;
#pragma unroll
  for (int i = 0; i < 4; ++i) {
    int u = tid + i * 256; int cr = u >> 4, q = u & 15;
    float4 v = *(const float4*)&feat[(size_t)(c0 + cr) * NN + n0 + q * 4];
    tile[cr][q*4+0] = v.x; tile[cr][q*4+1] = v.y; tile[cr][q*4+2] = v.z; tile[cr][q*4+3] = v.w;
  }
  __syncthreads();
#pragma unroll
  for (int i = 0; i < 4; ++i) {
    int u = tid + i * 256; int nr = u >> 4, q = u & 15;
    float iv = inv[n0 + nr];
    ushort4 h, l;
    float x0 = tile[q*4+0][nr] * iv, x1 = tile[q*4+1][nr] * iv;
    float x2 = tile[q*4+2][nr] * iv, x3 = tile[q*4+3][nr] * iv;
    h.x = f2bf(x0); l.x = f2bf(x0 - bf2f(h.x));
    h.y = f2bf(x1); l.y = f2bf(x1 - bf2f(h.y));
    h.z = f2bf(x2); l.z = f2bf(x2 - bf2f(h.z));
    h.w = f2bf(x3); l.w = f2bf(x3 - bf2f(h.w));
    size_t o = (size_t)(n0 + nr) * NC + c0 + q * 4;
    *(ushort4*)&Xhi[o] = h;
    *(ushort4*)&Xlo[o] = l;
  }
}

// ---------- 3. weight convert: W[k][n] fp32 -> Wt[n][k] bf16 (5 matrices) ----------
__global__ __launch_bounds__(256) void wcvt_kernel(const float* __restrict__ w0,
                                                   const float* __restrict__ w1,
                                                   const float* __restrict__ w2,
                                                   const float* __restrict__ w3,
                                                   const float* __restrict__ w4,
                                                   unsigned short* __restrict__ Wt) {
  __shared__ float tile[64][65];
  int z = blockIdx.z;
  const float* W = (z == 0) ? w0 : (z == 1) ? w1 : (z == 2) ? w2 : (z == 3) ? w3 : w4;
  int k0 = blockIdx.x * 64, n0 = blockIdx.y * 64;
  int tid = threadIdx.x;
#pragma unroll
  for (int i = 0; i < 4; ++i) {
    int u = tid + i * 256; int kr = u >> 4, q = u & 15;
    float4 v = *(const float4*)&W[(size_t)(k0 + kr) * NC + n0 + q * 4];
    tile[kr][q*4+0] = v.x; tile[kr][q*4+1] = v.y; tile[kr][q*4+2] = v.z; tile[kr][q*4+3] = v.w;
  }
  __syncthreads();
#pragma unroll
  for (int i = 0; i < 4; ++i) {
    int u = tid + i * 256; int nr = u >> 4, q = u & 15;
    ushort4 o;
    o.x = f2bf(tile[q*4+0][nr]); o.y = f2bf(tile[q*4+1][nr]);
    o.z = f2bf(tile[q*4+2][nr]); o.w = f2bf(tile[q*4+3][nr]);
    *(ushort4*)&Wt[(size_t)z * 65536 + (size_t)(n0 + nr) * NC + k0 + q * 4] = o;
  }
}

// ---------- 4. feat [B][C][N] -> xin [B*N][C] bf16 ----------
__global__ __launch_bounds__(256) void feat2bf_kernel(const float* __restrict__ feat,
                                                      unsigned short* __restrict__ xin) {
  __shared__ float tile[64][65];
  int n0 = blockIdx.x * 64, c0 = blockIdx.y * 64, b = blockIdx.z;
  int tid = threadIdx.x;
#pragma unroll
  for (int i = 0; i < 4; ++i) {
    int u = tid + i * 256; int cr = u >> 4, q = u & 15;
    float4 v = *(const float4*)&feat[((size_t)b * NC + c0 + cr) * NN + n0 + q * 4];
    tile[cr][q*4+0] = v.x; tile[cr][q*4+1] = v.y; tile[cr][q*4+2] = v.z; tile[cr][q*4+3] = v.w;
  }
  __syncthreads();
#pragma unroll
  for (int i = 0; i < 4; ++i) {
    int u = tid + i * 256; int nr = u >> 4, q = u & 15;
    ushort4 o;
    o.x = f2bf(tile[q*4+0][nr]); o.y = f2bf(tile[q*4+1][nr]);
    o.z = f2bf(tile[q*4+2][nr]); o.w = f2bf(tile[q*4+3][nr]);
    *(ushort4*)&xin[((size_t)(b << 12) + n0 + nr) * NC + c0 + q * 4] = o;
  }
}

// ---------- 5. fused sim (split-bf16 MFMA) + per-block per-row top-8 ----------
// grid (32, 32): full 4096x4096, no materialized panel. cand[row][32 tiles][8] ull.
__global__ __launch_bounds__(256) void simtop_kernel(const unsigned short* __restrict__ Xhi,
                                                     const unsigned short* __restrict__ Xlo,
                                                     ull* __restrict__ cand) {
  __shared__ __align__(16) char lds[73728];
  ushort_t (*sAh)[72] = (ushort_t(*)[72])(lds);
  ushort_t (*sAl)[72] = (ushort_t(*)[72])(lds + 18432);
  ushort_t (*sBh)[72] = (ushort_t(*)[72])(lds + 36864);
  ushort_t (*sBl)[72] = (ushort_t(*)[72])(lds + 55296);
  float    (*simT)[132] = (float(*)[132])(lds);       // 67584 B, aliases staging
  ull* scratch = (ull*)(lds);                          // [128][8], aliases again

  int tid = threadIdx.x, wave = tid >> 6, lane = tid & 63;
  int wm = wave >> 1, wn = wave & 1;
  int m0 = blockIdx.y * 128, n0 = blockIdx.x * 128;
  f4 acc[4][4];
#pragma unroll
  for (int i = 0; i < 4; ++i)
#pragma unroll
    for (int j = 0; j < 4; ++j) acc[i][j] = (f4){0.f, 0.f, 0.f, 0.f};

  for (int k0 = 0; k0 < NC; k0 += 64) {
#pragma unroll
    for (int i = 0; i < 4; ++i) {
      int u = tid + i * 256; int r = u >> 3, q = u & 7;
      size_t am = (size_t)(m0 + r) * NC + k0 + q * 8;
      size_t an = (size_t)(n0 + r) * NC + k0 + q * 8;
      *(uint4*)&sAh[r][q*8] = *(const uint4*)&Xhi[am];
      *(uint4*)&sAl[r][q*8] = *(const uint4*)&Xlo[am];
      *(uint4*)&sBh[r][q*8] = *(const uint4*)&Xhi[an];
      *(uint4*)&sBl[r][q*8] = *(const uint4*)&Xlo[an];
    }
    __syncthreads();
#pragma unroll
    for (int ks = 0; ks < 2; ++ks) {
      bf8 ah[4], al[4];
#pragma unroll
      for (int mf = 0; mf < 4; ++mf) {
        ah[mf] = *(const bf8*)&sAh[wm*64 + mf*16 + (lane & 15)][ks*32 + (lane >> 4)*8];
        al[mf] = *(const bf8*)&sAl[wm*64 + mf*16 + (lane & 15)][ks*32 + (lane >> 4)*8];
      }
#pragma unroll
      for (int nf = 0; nf < 4; ++nf) {
        bf8 bh = *(const bf8*)&sBh[wn*64 + nf*16 + (lane & 15)][ks*32 + (lane >> 4)*8];
        bf8 bl = *(const bf8*)&sBl[wn*64 + nf*16 + (lane & 15)][ks*32 + (lane >> 4)*8];
#pragma unroll
        for (int mf = 0; mf < 4; ++mf) {
          acc[mf][nf] = __builtin_amdgcn_mfma_f32_16x16x32_bf16(ah[mf], bh, acc[mf][nf], 0, 0, 0);
          acc[mf][nf] = __builtin_amdgcn_mfma_f32_16x16x32_bf16(ah[mf], bl, acc[mf][nf], 0, 0, 0);
          acc[mf][nf] = __builtin_amdgcn_mfma_f32_16x16x32_bf16(al[mf], bh, acc[mf][nf], 0, 0, 0);
        }
      }
    }
    __syncthreads();
  }

  // spill acc -> LDS fp32 tile (2-way bank aliasing only: 528 words/4-rows ≡ 16 mod 32)
#pragma unroll
  for (int mf = 0; mf < 4; ++mf) {
#pragma unroll
    for (int nf = 0; nf < 4; ++nf) {
      int cl = wn*64 + nf*16 + (lane & 15);
#pragma unroll
      for (int r = 0; r < 4; ++r) {
        simT[wm*64 + mf*16 + (lane >> 4)*4 + r][cl] = acc[mf][nf][r];
      }
    }
  }
  __syncthreads();

  // per-row top-8 over this block's 128 cols: 2 threads per row (halves of 64)
  int r_loc = tid >> 1, h = tid & 1;
  const float* rowp = &simT[r_loc][h * 64];
  ull b8[8] = {0,0,0,0,0,0,0,0};
#pragma unroll
  for (int i = 0; i < 16; ++i) {
    float4 v = *(const float4*)(rowp + i * 4);
    int jb = n0 + h*64 + i*4;
    ins8(b8, ((ull)enc_f(v.x) << 32) | (ull)(0xFFFFFFFFu - (unsigned)(jb + 0)));
    ins8(b8, ((ull)enc_f(v.y) << 32) | (ull)(0xFFFFFFFFu - (unsigned)(jb + 1)));
    ins8(b8, ((ull)enc_f(v.z) << 32) | (ull)(0xFFFFFFFFu - (unsigned)(jb + 2)));
    ins8(b8, ((ull)enc_f(v.w) << 32) | (ull)(0xFFFFFFFFu - (unsigned)(jb + 3)));
  }
  __syncthreads();  // all simT reads done before scratch overwrite
  if (h) {
#pragma unroll
    for (int k = 0; k < 8; ++k) scratch[r_loc * 8 + k] = b8[k];
  }
  __syncthreads();
  if (!h) {
#pragma unroll
    for (int k = 0; k < 8; ++k) ins8(b8, scratch[r_loc * 8 + k]);
    ull* dst = cand + (size_t)(m0 + r_loc) * 256 + blockIdx.x * 8;
#pragma unroll
    for (int k = 0; k < 8; ++k) dst[k] = b8[k];
  }
}

// ---------- 6. merge per-tile candidates -> exact global top-8 (+ counts) ----------
__global__ __launch_bounds__(256) void merge_kernel(const ull* __restrict__ cand,
                                                    int* __restrict__ idx8,
                                                    int* __restrict__ counts) {
  int row = blockIdx.x * 256 + threadIdx.x;
  const ull* cp = cand + (size_t)row * 256;
  ull b8[8] = {0,0,0,0,0,0,0,0};
  for (int g = 0; g < 32; ++g) {
#pragma unroll 1
    for (int k = 0; k < 8; ++k) {
      ull key = cp[g * 8 + k];
      if (key <= b8[7]) break;  // per-tile list sorted descending -> exact early exit
      ins8(b8, key);
    }
  }
#pragma unroll
  for (int k = 0; k < 8; ++k) {
    int j = (int)(0xFFFFFFFFu - (unsigned)(b8[k] & 0xFFFFFFFFull));
    idx8[row * 8 + k] = j;
    atomicAdd(&counts[j], 1);
  }
}

// ---------- 7. CSR prefix scan (exclusive) + cursor init ----------
__global__ __launch_bounds__(256) void scan_kernel(const int* __restrict__ counts,
                                                   int* __restrict__ offsets,
                                                   int* __restrict__ cursor) {
  __shared__ int ssum[256];
  __shared__ int sbase[257];
  int t = threadIdx.x;
  int loc[16];
  int s = 0;
#pragma unroll
  for (int i = 0; i < 16; ++i) { loc[i] = s; s += counts[t*16 + i]; }
  ssum[t] = s;
  __syncthreads();
  if (t == 0) {
    int acc = 0;
    for (int i = 0; i < 256; ++i) { sbase[i] = acc; acc += ssum[i]; }
    sbase[256] = acc;
  }
  __syncthreads();
  int b0 = sbase[t];
#pragma unroll
  for (int i = 0; i < 16; ++i) {
    int off = b0 + loc[i];
    offsets[t*16 + i] = off;
    cursor [t*16 + i] = off;
  }
  if (t == 0) offsets[NN] = sbase[256];
}

// ---------- 8. CSR fill ----------
__global__ __launch_bounds__(256) void fill_kernel(const int* __restrict__ idx8,
                                                   int* __restrict__ cursor,
                                                   int* __restrict__ edgelist) {
  int t = blockIdx.x * 256 + threadIdx.x;  // 32768 pairs
  int n = idx8[t];
  int pos = atomicAdd(&cursor[n], 1);
  edgelist[pos] = t >> 3;
}

// ---------- 9. bf16 MFMA GEMM 128x128 (512 thr): out = A·Wt^T + bias ----------
// OUTF32: fp32 output (proj). BNS: fused BN partial sums (proj only).
template<int OUTF32, int BNS>
__global__ __launch_bounds__(512) void gemm_bf16_kernel(const unsigned short* __restrict__ A,
                                                        const unsigned short* __restrict__ Wt,
                                                        const float* __restrict__ bias,
                                                        void* __restrict__ outp,
                                                        float* __restrict__ bnsum) {
  __shared__ ushort_t sA[128][72];
  __shared__ ushort_t sB[128][72];
  int tid = threadIdx.x, wave = tid >> 6, lane = tid & 63;
  int wm = wave >> 2, wn = wave & 3;           // 2 x 4 waves
  int n0 = blockIdx.x * 128, m0 = blockIdx.y * 128;
  f4 acc[4][2];
#pragma unroll
  for (int i = 0; i < 4; ++i)
#pragma unroll
    for (int j = 0; j < 2; ++j) acc[i][j] = (f4){0.f, 0.f, 0.f, 0.f};

  for (int k0 = 0; k0 < NC; k0 += 64) {
#pragma unroll
    for (int i = 0; i < 2; ++i) {
      int u = tid + i * 512; int r = u >> 3, q = u & 7;
      *(uint4*)&sA[r][q*8] = *(const uint4*)&A [(size_t)(m0 + r) * NC + k0 + q * 8];
      *(uint4*)&sB[r][q*8] = *(const uint4*)&Wt[(size_t)(n0 + r) * NC + k0 + q * 8];
    }
    __syncthreads();
#pragma unroll
    for (int ks = 0; ks < 2; ++ks) {
      bf8 a[4], b[2];
#pragma unroll
      for (int mf = 0; mf < 4; ++mf)
        a[mf] = *(const bf8*)&sA[wm*64 + mf*16 + (lane & 15)][ks*32 + (lane >> 4)*8];
#pragma unroll
      for (int nf = 0; nf < 2; ++nf)
        b[nf] = *(const bf8*)&sB[wn*32 + nf*16 + (lane & 15)][ks*32 + (lane >> 4)*8];
#pragma unroll
      for (int nf = 0; nf < 2; ++nf)
#pragma unroll
        for (int mf = 0; mf < 4; ++mf)
          acc[mf][nf] = __builtin_amdgcn_mfma_f32_16x16x32_bf16(a[mf], b[nf], acc[mf][nf], 0, 0, 0);
    }
    __syncthreads();
  }
#pragma unroll
  for (int nf = 0; nf < 2; ++nf) {
    int n = n0 + wn*32 + nf*16 + (lane & 15);
    float bi = bias[n];
    float s1 = 0.f, s2 = 0.f;
#pragma unroll
    for (int mf = 0; mf < 4; ++mf) {
#pragma unroll
      for (int r = 0; r < 4; ++r) {
        int m = m0 + wm*64 + mf*16 + (lane >> 4)*4 + r;
        float v = acc[mf][nf][r] + bi;
        if (OUTF32) ((float*)outp)[(size_t)m * NC + n] = v;
        else ((unsigned short*)outp)[(size_t)m * NC + n] = f2bf(v);
        if (BNS) { s1 += v; s2 = fmaf(v, v, s2); }
      }
    }
    if (BNS) {
      s1 += __shfl_xor(s1, 16); s1 += __shfl_xor(s1, 32);
      s2 += __shfl_xor(s2, 16); s2 += __shfl_xor(s2, 32);
      if (lane < 16) {
        atomicAdd(&bnsum[n], s1);
        atomicAdd(&bnsum[NC + n], s2);
      }
    }
  }
}

// ---------- 10. edge gather (bf16): ef[b,e,:] = 1/8 sum_k xt[b, idx[e][k], :] ----------
__global__ __launch_bounds__(256) void gather_kernel(const unsigned short* __restrict__ xt,
                                                     const int* __restrict__ idx8,
                                                     unsigned short* __restrict__ ef) {
  int b = blockIdx.y;
  int e = blockIdx.x * 4 + (threadIdx.x >> 6);
  int lane = threadIdx.x & 63;
  float s0 = 0, s1 = 0, s2 = 0, s3 = 0;
  const int* ip = &idx8[e * 8];
#pragma unroll
  for (int k = 0; k < 8; ++k) {
    int n = ip[k];
    uint2 v = *(const uint2*)&xt[((size_t)((b << 12) + n)) * NC + lane * 4];
    s0 += bf2f((unsigned short)(v.x & 0xFFFF)); s1 += bf2f((unsigned short)(v.x >> 16));
    s2 += bf2f((unsigned short)(v.y & 0xFFFF)); s3 += bf2f((unsigned short)(v.y >> 16));
  }
  uint2 o;
  o.x = (unsigned)f2bf(s0 * 0.125f) | ((unsigned)f2bf(s1 * 0.125f) << 16);
  o.y = (unsigned)f2bf(s2 * 0.125f) | ((unsigned)f2bf(s3 * 0.125f) << 16);
  *(uint2*)&ef[((size_t)((b << 12) + e)) * NC + lane * 4] = o;
}

// ---------- 11. node scatter (bf16): relu(1/8 sum_{e∋n} xp[b,e,:]) (+bf16 residual) ----------
template<int MODE>
__global__ __launch_bounds__(256) void scatter_kernel(const unsigned short* __restrict__ xp,
                                                      const int* __restrict__ offsets,
                                                      const int* __restrict__ edgelist,
                                                      const unsigned short* __restrict__ res,
                                                      unsigned short* __restrict__ outb) {
  int b = blockIdx.y;
  int n = blockIdx.x * 4 + (threadIdx.x >> 6);
  int lane = threadIdx.x & 63;
  int s0i = offsets[n], s1i = offsets[n + 1];
  float s0 = 0, s1 = 0, s2 = 0, s3 = 0;
  for (int j = s0i; j < s1i; ++j) {
    int e = edgelist[j];
    uint2 v = *(const uint2*)&xp[((size_t)((b << 12) + e)) * NC + lane * 4];
    s0 += bf2f((unsigned short)(v.x & 0xFFFF)); s1 += bf2f((unsigned short)(v.x >> 16));
    s2 += bf2f((unsigned short)(v.y & 0xFFFF)); s3 += bf2f((unsigned short)(v.y >> 16));
  }
  s0 = fmaxf(s0 * 0.125f, 0.f); s1 = fmaxf(s1 * 0.125f, 0.f);
  s2 = fmaxf(s2 * 0.125f, 0.f); s3 = fmaxf(s3 * 0.125f, 0.f);
  size_t o = ((size_t)((b << 12) + n)) * NC + lane * 4;
  if (MODE == 1) {
    uint2 v = *(const uint2*)&res[o];
    s0 += bf2f((unsigned short)(v.x & 0xFFFF)); s1 += bf2f((unsigned short)(v.x >> 16));
    s2 += bf2f((unsigned short)(v.y & 0xFFFF)); s3 += bf2f((unsigned short)(v.y >> 16));
  }
  uint2 ov;
  ov.x = (unsigned)f2bf(s0) | ((unsigned)f2bf(s1) << 16);
  ov.y = (unsigned)f2bf(s2) | ((unsigned)f2bf(s3) << 16);
  *(uint2*)&outb[o] = ov;
}

// ---------- 12. transpose + BN (inline stats->affine) + residual ----------
__global__ __launch_bounds__(256) void final_kernel(const float* __restrict__ y,
                                                    const float* __restrict__ feat,
                                                    const float* __restrict__ bnsum,
                                                    const float* __restrict__ gam,
                                                    const float* __restrict__ bet,
                                                    float* __restrict__ out) {
  __shared__ float tile[64][65];
  __shared__ float sa_[64], sb_[64];
  int n0 = blockIdx.x * 64;
  int c0 = blockIdx.y * 64;
  int b  = blockIdx.z;
  int tid = threadIdx.x;
  if (tid < 64) {
    const float invn = 1.f / (float)(NB * NN);
    int c = c0 + tid;
    float mean = bnsum[c] * invn;
    float var  = bnsum[NC + c] * invn - mean * mean;
    float a = gam[c] * rsqrtf(var + 1e-5f);
    sa_[tid] = a;
    sb_[tid] = bet[c] - mean * a;
  }
  int n_l = tid >> 2;
  int q   = tid & 3;
  const float4* y4 = (const float4*)y;
#pragma unroll
  for (int i = 0; i < 4; ++i) {
    int cl = q * 16 + i * 4;
    float4 v = y4[(size_t)(b * NN + n0 + n_l) * 64 + ((c0 + cl) >> 2)];
    tile[n_l][cl+0] = v.x; tile[n_l][cl+1] = v.y; tile[n_l][cl+2] = v.z; tile[n_l][cl+3] = v.w;
  }
  __syncthreads();
  int cl2 = tid >> 6;
  int nl2 = tid & 63;
#pragma unroll
  for (int p = 0; p < 16; ++p) {
    int ci = p * 4 + cl2;
    float a = sa_[ci], bb = sb_[ci];
    size_t o = (size_t)b * (NC * NN) + (size_t)(c0 + ci) * NN + n0 + nl2;
    out[o] = feat[o] + fmaf(a, tile[nl2][ci], bb);
  }
}

}  // namespace

extern "C" void kernel_launch(void* const* d_in, const int* in_sizes, int n_in,
                              void* d_out, int out_size, void* d_ws, size_t ws_size,
                              hipStream_t stream) {
  (void)in_sizes; (void)n_in; (void)out_size; (void)ws_size;
  const float* feat = (const float*)d_in[0];
  const float* t0w  = (const float*)d_in[1];
  const float* t0b  = (const float*)d_in[2];
  const float* p0w  = (const float*)d_in[3];
  const float* p0b  = (const float*)d_in[4];
  const float* t1w  = (const float*)d_in[5];
  const float* t1b  = (const float*)d_in[6];
  const float* p1w  = (const float*)d_in[7];
  const float* p1b  = (const float*)d_in[8];
  const float* pw   = (const float*)d_in[9];
  const float* pb   = (const float*)d_in[10];
  const float* gam  = (const float*)d_in[11];
  const float* bet  = (const float*)d_in[12];
  float* out = (float*)d_out;

  // workspace layout (~77 MiB)
  char* ws = (char*)d_ws;
  float*          y   = (float*)ws;                          // 16 MiB fp32 [B*N][C]
  unsigned short* xin = (unsigned short*)(ws + (16u << 20)); // 8 MiB each
  unsigned short* xt  = (unsigned short*)(ws + (24u << 20));
  unsigned short* ef  = (unsigned short*)(ws + (32u << 20));
  unsigned short* xp  = (unsigned short*)(ws + (40u << 20));
  unsigned short* x1  = (unsigned short*)(ws + (48u << 20));
  unsigned short* x2  = (unsigned short*)(ws + (56u << 20));
  unsigned short* Xhi = (unsigned short*)(ws + (64u << 20)); // 2 MiB
  unsigned short* Xlo = (unsigned short*)(ws + (66u << 20)); // 2 MiB
  ull*            cand = (ull*)(ws + (68u << 20));           // 8 MiB (4096*256 ull)
  char* sm = ws + (76u << 20);
  unsigned short* Wt  = (unsigned short*)sm;                 // 5*128 KiB
  int*   idx8     = (int*)(sm + 655360);                     // 128 KiB
  int*   counts   = (int*)(sm + 786432);                     // 16 KiB
  int*   offsets  = (int*)(sm + 802816);                     // 16 KiB + 4
  int*   cursor   = (int*)(sm + 819456);                     // 16 KiB
  int*   edgelist = (int*)(sm + 835840);                     // 128 KiB
  float* inv      = (float*)(sm + 966912);                   // 16 KiB
  float* bnsum    = (float*)(sm + 983296);                   // 2 KiB

  norm_kernel<<<NN / 256, 256, 0, stream>>>(feat, inv, counts, bnsum);
  xpose_split_kernel<<<dim3(64, 4), 256, 0, stream>>>(feat, inv, Xhi, Xlo);
  wcvt_kernel<<<dim3(4, 4, 5), 256, 0, stream>>>(t0w, p0w, t1w, p1w, pw, Wt);
  feat2bf_kernel<<<dim3(64, 4, 4), 256, 0, stream>>>(feat, xin);

  // fused sim + per-tile top-8 (no materialized 4096^2 panel)
  simtop_kernel<<<dim3(32, 32), 256, 0, stream>>>(Xhi, Xlo, cand);
  merge_kernel<<<16, 256, 0, stream>>>(cand, idx8, counts);
  scan_kernel<<<1, 256, 0, stream>>>(counts, offsets, cursor);
  fill_kernel<<<128, 256, 0, stream>>>(idx8, cursor, edgelist);

  // layer 0
  gemm_bf16_kernel<0,0><<<dim3(2, 128), 512, 0, stream>>>(xin, Wt + 0*65536, t0b, xt, nullptr);
  gather_kernel<<<dim3(1024, 4), 256, 0, stream>>>(xt, idx8, ef);
  gemm_bf16_kernel<0,0><<<dim3(2, 128), 512, 0, stream>>>(ef, Wt + 1*65536, p0b, xp, nullptr);
  scatter_kernel<0><<<dim3(1024, 4), 256, 0, stream>>>(xp, offsets, edgelist, nullptr, x1);
  // layer 1
  gemm_bf16_kernel<0,0><<<dim3(2, 128), 512, 0, stream>>>(x1, Wt + 2*65536, t1b, xt, nullptr);
  gather_kernel<<<dim3(1024, 4), 256, 0, stream>>>(xt, idx8, ef);
  gemm_bf16_kernel<0,0><<<dim3(2, 128), 512, 0, stream>>>(ef, Wt + 3*65536, p1b, xp, nullptr);
  scatter_kernel<1><<<dim3(1024, 4), 256, 0, stream>>>(xp, offsets, edgelist, x1, x2);
  // proj (fp32 out) + fused BN stats
  gemm_bf16_kernel<1,1><<<dim3(2, 128), 512, 0, stream>>>(x2, Wt + 4*65536, pb, y, bnsum);

  final_kernel<<<dim3(64, 4, 4), 256, 0, stream>>>(y, feat, bnsum, gam, bet, out);
}

// Round 5
// 334.052 us; speedup vs baseline: 1.9483x; 1.1061x over previous
//
#include <hip/hip_runtime.h>

namespace {

constexpr int NB = 4;
constexpr int NC = 256;   // C == HID
constexpr int NN = 4096;  // 64*64

typedef __attribute__((ext_vector_type(8))) short bf8;
typedef __attribute__((ext_vector_type(4))) float f4;
typedef unsigned short ushort_t;
typedef unsigned long long ull;

__device__ __forceinline__ float bf2f(unsigned short u) {
  return __uint_as_float(((unsigned)u) << 16);
}
__device__ __forceinline__ unsigned short f2bf(float f) {  // RNE
  unsigned x = __float_as_uint(f);
  return (unsigned short)((x + 0x7FFFu + ((x >> 16) & 1u)) >> 16);
}
__device__ __forceinline__ unsigned enc_f(float f) {
  unsigned u = __float_as_uint(f);
  return (u & 0x80000000u) ? ~u : (u | 0x80000000u);  // monotonic float->uint
}

// sorted-descending 8-element insert (keys pack (val asc-enc, ~idx))
__device__ __forceinline__ void ins8(ull* b, ull k) {
  if (k <= b[7]) return;
  b[7] = k;
#pragma unroll
  for (int p = 7; p >= 1; --p) {
    if (b[p] > b[p-1]) { ull t = b[p]; b[p] = b[p-1]; b[p-1] = t; }
  }
}

__device__ __forceinline__ ull shfl_xor_ull(ull v, int mask) {
  unsigned lo = (unsigned)(v & 0xFFFFFFFFull), hi = (unsigned)(v >> 32);
  lo = (unsigned)__shfl_xor((int)lo, mask);
  hi = (unsigned)__shfl_xor((int)hi, mask);
  return ((ull)hi << 32) | (ull)lo;
}

// merge partner lists via shfl butterfly (levels 1..maxs), snapshot-then-insert
template<int MAXS>
__device__ __forceinline__ void shfl_merge8(ull* b) {
#pragma unroll
  for (int s = 1; s <= MAXS; s <<= 1) {
    ull tmp[8];
#pragma unroll
    for (int k = 0; k < 8; ++k) tmp[k] = shfl_xor_ull(b[k], s);
#pragma unroll
    for (int k = 0; k < 8; ++k) ins8(b, tmp[k]);
  }
}

// ---------- 1. inverse row norms of batch-0 features (+ zero counts/bnsum) ----------
__global__ __launch_bounds__(256) void norm_kernel(const float* __restrict__ feat,
                                                   float* __restrict__ inv,
                                                   int* __restrict__ counts,
                                                   float* __restrict__ bnsum) {
  int n = blockIdx.x * 256 + threadIdx.x;
  counts[n] = 0;
  if (n < 2 * NC) bnsum[n] = 0.f;
  float ss = 0.f;
  for (int c = 0; c < NC; ++c) { float v = feat[(size_t)c * NN + n]; ss = fmaf(v, v, ss); }
  inv[n] = 1.f / fmaxf(sqrtf(ss), 1e-12f);
}

// ---------- 2. transpose + normalize + split: Xhi/Xlo [N][C] bf16 ----------
__global__ __launch_bounds__(256) void xpose_split_kernel(const float* __restrict__ feat,
                                                          const float* __restrict__ inv,
                                                          unsigned short* __restrict__ Xhi,
                                                          unsigned short* __restrict__ Xlo) {
  __shared__ float tile[64][65];
  int n0 = blockIdx.x * 64, c0 = blockIdx.y * 64;
  int tid = threadIdx.x;
#pragma unroll
  for (int i = 0; i < 4; ++i) {
    int u = tid + i * 256; int cr = u >> 4, q = u & 15;
    float4 v = *(const float4*)&feat[(size_t)(c0 + cr) * NN + n0 + q * 4];
    tile[cr][q*4+0] = v.x; tile[cr][q*4+1] = v.y; tile[cr][q*4+2] = v.z; tile[cr][q*4+3] = v.w;
  }
  __syncthreads();
#pragma unroll
  for (int i = 0; i < 4; ++i) {
    int u = tid + i * 256; int nr = u >> 4, q = u & 15;
    float iv = inv[n0 + nr];
    ushort4 h, l;
    float x0 = tile[q*4+0][nr] * iv, x1 = tile[q*4+1][nr] * iv;
    float x2 = tile[q*4+2][nr] * iv, x3 = tile[q*4+3][nr] * iv;
    h.x = f2bf(x0); l.x = f2bf(x0 - bf2f(h.x));
    h.y = f2bf(x1); l.y = f2bf(x1 - bf2f(h.y));
    h.z = f2bf(x2); l.z = f2bf(x2 - bf2f(h.z));
    h.w = f2bf(x3); l.w = f2bf(x3 - bf2f(h.w));
    size_t o = (size_t)(n0 + nr) * NC + c0 + q * 4;
    *(ushort4*)&Xhi[o] = h;
    *(ushort4*)&Xlo[o] = l;
  }
}

// ---------- 3. weight convert: W[k][n] fp32 -> Wt[n][k] bf16 (5 matrices) ----------
__global__ __launch_bounds__(256) void wcvt_kernel(const float* __restrict__ w0,
                                                   const float* __restrict__ w1,
                                                   const float* __restrict__ w2,
                                                   const float* __restrict__ w3,
                                                   const float* __restrict__ w4,
                                                   unsigned short* __restrict__ Wt) {
  __shared__ float tile[64][65];
  int z = blockIdx.z;
  const float* W = (z == 0) ? w0 : (z == 1) ? w1 : (z == 2) ? w2 : (z == 3) ? w3 : w4;
  int k0 = blockIdx.x * 64, n0 = blockIdx.y * 64;
  int tid = threadIdx.x;
#pragma unroll
  for (int i = 0; i < 4; ++i) {
    int u = tid + i * 256; int kr = u >> 4, q = u & 15;
    float4 v = *(const float4*)&W[(size_t)(k0 + kr) * NC + n0 + q * 4];
    tile[kr][q*4+0] = v.x; tile[kr][q*4+1] = v.y; tile[kr][q*4+2] = v.z; tile[kr][q*4+3] = v.w;
  }
  __syncthreads();
#pragma unroll
  for (int i = 0; i < 4; ++i) {
    int u = tid + i * 256; int nr = u >> 4, q = u & 15;
    ushort4 o;
    o.x = f2bf(tile[q*4+0][nr]); o.y = f2bf(tile[q*4+1][nr]);
    o.z = f2bf(tile[q*4+2][nr]); o.w = f2bf(tile[q*4+3][nr]);
    *(ushort4*)&Wt[(size_t)z * 65536 + (size_t)(n0 + nr) * NC + k0 + q * 4] = o;
  }
}

// ---------- 4. feat [B][C][N] -> xin [B*N][C] bf16 ----------
__global__ __launch_bounds__(256) void feat2bf_kernel(const float* __restrict__ feat,
                                                      unsigned short* __restrict__ xin) {
  __shared__ float tile[64][65];
  int n0 = blockIdx.x * 64, c0 = blockIdx.y * 64, b = blockIdx.z;
  int tid = threadIdx.x;
#pragma unroll
  for (int i = 0; i < 4; ++i) {
    int u = tid + i * 256; int cr = u >> 4, q = u & 15;
    float4 v = *(const float4*)&feat[((size_t)b * NC + c0 + cr) * NN + n0 + q * 4];
    tile[cr][q*4+0] = v.x; tile[cr][q*4+1] = v.y; tile[cr][q*4+2] = v.z; tile[cr][q*4+3] = v.w;
  }
  __syncthreads();
#pragma unroll
  for (int i = 0; i < 4; ++i) {
    int u = tid + i * 256; int nr = u >> 4, q = u & 15;
    ushort4 o;
    o.x = f2bf(tile[q*4+0][nr]); o.y = f2bf(tile[q*4+1][nr]);
    o.z = f2bf(tile[q*4+2][nr]); o.w = f2bf(tile[q*4+3][nr]);
    *(ushort4*)&xin[((size_t)(b << 12) + n0 + nr) * NC + c0 + q * 4] = o;
  }
}

// ---------- 5. symmetric fused sim (split-bf16 MFMA) + dual top-8 extraction ----------
// 528 upper-triangle blocks (pj<=pi): rows panel pj, cols panel pi. 512 thr / 8 waves.
// Row-extract -> cand[m0+r][chunk pi]; col-extract (pi!=pj) -> cand[n0+c][chunk pj].
__global__ __launch_bounds__(512) void simtop_kernel(const unsigned short* __restrict__ Xhi,
                                                     const unsigned short* __restrict__ Xlo,
                                                     ull* __restrict__ cand) {
  __shared__ __align__(16) char lds[73728];
  ushort_t (*sAh)[72] = (ushort_t(*)[72])(lds);
  ushort_t (*sAl)[72] = (ushort_t(*)[72])(lds + 18432);
  ushort_t (*sBh)[72] = (ushort_t(*)[72])(lds + 36864);
  ushort_t (*sBl)[72] = (ushort_t(*)[72])(lds + 55296);
  float    (*simT)[132] = (float(*)[132])(lds);   // 67584 B, aliases staging after compute

  int tid = threadIdx.x, wave = tid >> 6, lane = tid & 63;
  int wm = wave >> 2, wn = wave & 3;   // 2 x 4 waves, wave tile 64x32
  // triangular decode bid -> (pj <= pi)
  int bid = blockIdx.x;
  int pi = (int)((sqrtf(8.f * (float)bid + 1.f) - 1.f) * 0.5f);
  while ((pi + 1) * (pi + 2) / 2 <= bid) ++pi;
  while (pi * (pi + 1) / 2 > bid) --pi;
  int pj = bid - pi * (pi + 1) / 2;
  int m0 = pj * 128, n0 = pi * 128;

  f4 acc[4][2];
#pragma unroll
  for (int i = 0; i < 4; ++i)
#pragma unroll
    for (int j = 0; j < 2; ++j) acc[i][j] = (f4){0.f, 0.f, 0.f, 0.f};

  for (int k0 = 0; k0 < NC; k0 += 64) {
#pragma unroll
    for (int i = 0; i < 2; ++i) {
      int u = tid + i * 512; int r = u >> 3, q = u & 7;
      int qp = (q ^ ((r >> 1) & 7)) * 8;   // XOR-swizzled store col
      size_t am = (size_t)(m0 + r) * NC + k0 + q * 8;
      size_t an = (size_t)(n0 + r) * NC + k0 + q * 8;
      *(uint4*)&sAh[r][qp] = *(const uint4*)&Xhi[am];
      *(uint4*)&sAl[r][qp] = *(const uint4*)&Xlo[am];
      *(uint4*)&sBh[r][qp] = *(const uint4*)&Xhi[an];
      *(uint4*)&sBl[r][qp] = *(const uint4*)&Xlo[an];
    }
    __syncthreads();
#pragma unroll
    for (int ks = 0; ks < 2; ++ks) {
      int qr = ks * 4 + (lane >> 4);
      bf8 ah[4], al[4], bh[2], bl[2];
#pragma unroll
      for (int mf = 0; mf < 4; ++mf) {
        int rr = wm*64 + mf*16 + (lane & 15);
        int qp = (qr ^ ((rr >> 1) & 7)) * 8;
        ah[mf] = *(const bf8*)&sAh[rr][qp];
        al[mf] = *(const bf8*)&sAl[rr][qp];
      }
#pragma unroll
      for (int nf = 0; nf < 2; ++nf) {
        int rr = wn*32 + nf*16 + (lane & 15);
        int qp = (qr ^ ((rr >> 1) & 7)) * 8;
        bh[nf] = *(const bf8*)&sBh[rr][qp];
        bl[nf] = *(const bf8*)&sBl[rr][qp];
      }
#pragma unroll
      for (int nf = 0; nf < 2; ++nf)
#pragma unroll
        for (int mf = 0; mf < 4; ++mf) {
          acc[mf][nf] = __builtin_amdgcn_mfma_f32_16x16x32_bf16(ah[mf], bh[nf], acc[mf][nf], 0, 0, 0);
          acc[mf][nf] = __builtin_amdgcn_mfma_f32_16x16x32_bf16(ah[mf], bl[nf], acc[mf][nf], 0, 0, 0);
          acc[mf][nf] = __builtin_amdgcn_mfma_f32_16x16x32_bf16(al[mf], bh[nf], acc[mf][nf], 0, 0, 0);
        }
    }
    __syncthreads();
  }

  // spill acc -> LDS fp32 tile
#pragma unroll
  for (int mf = 0; mf < 4; ++mf)
#pragma unroll
    for (int nf = 0; nf < 2; ++nf) {
      int cl = wn*32 + nf*16 + (lane & 15);
#pragma unroll
      for (int r = 0; r < 4; ++r)
        simT[wm*64 + mf*16 + (lane >> 4)*4 + r][cl] = acc[mf][nf][r];
    }
  __syncthreads();

  // row extraction: 4 threads per row, staggered float4 reads, shfl merge
  {
    int rrow = tid >> 2, q4 = tid & 3;
    ull b8[8] = {0,0,0,0,0,0,0,0};
#pragma unroll
    for (int i = 0; i < 8; ++i) {
      int cofs = q4 * 32 + (((i + q4 * 2) & 7)) * 4;
      float4 v = *(const float4*)&simT[rrow][cofs];
      int jb = n0 + cofs;
      ins8(b8, ((ull)enc_f(v.x) << 32) | (ull)(0xFFFFFFFFu - (unsigned)(jb + 0)));
      ins8(b8, ((ull)enc_f(v.y) << 32) | (ull)(0xFFFFFFFFu - (unsigned)(jb + 1)));
      ins8(b8, ((ull)enc_f(v.z) << 32) | (ull)(0xFFFFFFFFu - (unsigned)(jb + 2)));
      ins8(b8, ((ull)enc_f(v.w) << 32) | (ull)(0xFFFFFFFFu - (unsigned)(jb + 3)));
    }
    shfl_merge8<2>(b8);
    if (q4 == 0) {
      ull* dst = cand + (size_t)(m0 + rrow) * 256 + pi * 8;
#pragma unroll
      for (int k = 0; k < 8; ++k) dst[k] = b8[k];
    }
  }

  // column extraction (transposed candidates) for off-diagonal blocks
  if (pi != pj) {
    int ccol = tid >> 2, seg = tid & 3;
    ull c8[8] = {0,0,0,0,0,0,0,0};
    for (int i = 0; i < 32; ++i) {
      int rr = seg * 32 + ((i + seg) & 31);   // stagger to spread banks
      float v = simT[rr][ccol];
      int jb = m0 + rr;
      ins8(c8, ((ull)enc_f(v) << 32) | (ull)(0xFFFFFFFFu - (unsigned)jb));
    }
    shfl_merge8<2>(c8);
    if (seg == 0) {
      ull* dst = cand + (size_t)(n0 + ccol) * 256 + pj * 8;
#pragma unroll
      for (int k = 0; k < 8; ++k) dst[k] = c8[k];
    }
  }
}

// ---------- 6. merge per-tile candidates -> exact global top-8 (+ counts) ----------
// 8 threads per row; each scans 4 sorted chunk-lists with early-break, shfl merge.
__global__ __launch_bounds__(256) void merge_kernel(const ull* __restrict__ cand,
                                                    int* __restrict__ idx8,
                                                    int* __restrict__ counts) {
  int t = blockIdx.x * 256 + threadIdx.x;   // 32768 = 4096 rows x 8
  int row = t >> 3, part = t & 7;
  const ull* cp = cand + (size_t)row * 256 + part * 32;
  ull b8[8] = {0,0,0,0,0,0,0,0};
  for (int g = 0; g < 4; ++g) {
#pragma unroll 1
    for (int k = 0; k < 8; ++k) {
      ull key = cp[g * 8 + k];
      if (key <= b8[7]) break;
      ins8(b8, key);
    }
  }
  shfl_merge8<4>(b8);
  if (part == 0) {
#pragma unroll
    for (int k = 0; k < 8; ++k) {
      int j = (int)(0xFFFFFFFFu - (unsigned)(b8[k] & 0xFFFFFFFFull));
      idx8[row * 8 + k] = j;
      atomicAdd(&counts[j], 1);
    }
  }
}

// ---------- 7. CSR prefix scan (exclusive) + cursor init ----------
__global__ __launch_bounds__(256) void scan_kernel(const int* __restrict__ counts,
                                                   int* __restrict__ offsets,
                                                   int* __restrict__ cursor) {
  __shared__ int ssum[256];
  __shared__ int sbase[257];
  int t = threadIdx.x;
  int loc[16];
  int s = 0;
#pragma unroll
  for (int i = 0; i < 16; ++i) { loc[i] = s; s += counts[t*16 + i]; }
  ssum[t] = s;
  __syncthreads();
  if (t == 0) {
    int acc = 0;
    for (int i = 0; i < 256; ++i) { sbase[i] = acc; acc += ssum[i]; }
    sbase[256] = acc;
  }
  __syncthreads();
  int b0 = sbase[t];
#pragma unroll
  for (int i = 0; i < 16; ++i) {
    int off = b0 + loc[i];
    offsets[t*16 + i] = off;
    cursor [t*16 + i] = off;
  }
  if (t == 0) offsets[NN] = sbase[256];
}

// ---------- 8. CSR fill ----------
__global__ __launch_bounds__(256) void fill_kernel(const int* __restrict__ idx8,
                                                   int* __restrict__ cursor,
                                                   int* __restrict__ edgelist) {
  int t = blockIdx.x * 256 + threadIdx.x;  // 32768 pairs
  int n = idx8[t];
  int pos = atomicAdd(&cursor[n], 1);
  edgelist[pos] = t >> 3;
}

// ---------- 9. bf16 MFMA GEMM 128x128 (512 thr), optional fused edge-gather ----------
// GATHER: A-tile rows are edges; stage 1/8 * sum of 8 xt rows (identical numerics to
// the standalone gather: fp32 sum in k-order, *0.125, f2bf).
template<int OUTF32, int BNS, int GATHER>
__global__ __launch_bounds__(512) void gemm_bf16_kernel(const unsigned short* __restrict__ A,
                                                        const unsigned short* __restrict__ Wt,
                                                        const float* __restrict__ bias,
                                                        void* __restrict__ outp,
                                                        float* __restrict__ bnsum,
                                                        const int* __restrict__ idx8) {
  __shared__ ushort_t sA[128][72];
  __shared__ ushort_t sB[128][72];
  __shared__ int sIdx[128][8];
  int tid = threadIdx.x, wave = tid >> 6, lane = tid & 63;
  int wm = wave >> 2, wn = wave & 3;           // 2 x 4 waves
  int n0 = blockIdx.x * 128, m0 = blockIdx.y * 128;
  size_t bbase = 0;
  if constexpr (GATHER) {
    int e0 = m0 & 4095;
    bbase = ((size_t)(m0 >> 12) << 12) * NC;   // batch base row offset in xt
#pragma unroll
    for (int u = tid; u < 1024; u += 512) ((int*)sIdx)[u] = idx8[e0 * 8 + u];
    __syncthreads();
  }
  f4 acc[4][2];
#pragma unroll
  for (int i = 0; i < 4; ++i)
#pragma unroll
    for (int j = 0; j < 2; ++j) acc[i][j] = (f4){0.f, 0.f, 0.f, 0.f};

  for (int k0 = 0; k0 < NC; k0 += 64) {
#pragma unroll
    for (int i = 0; i < 2; ++i) {
      int u = tid + i * 512; int r = u >> 3, q = u & 7;
      int qp = (q ^ ((r >> 1) & 7)) * 8;
      if constexpr (GATHER) {
        float s[8] = {0.f,0.f,0.f,0.f,0.f,0.f,0.f,0.f};
#pragma unroll
        for (int k = 0; k < 8; ++k) {
          int nn = sIdx[r][k];
          uint4 v = *(const uint4*)&A[bbase + (size_t)nn * NC + k0 + q * 8];
          s[0] += bf2f((unsigned short)(v.x & 0xFFFF)); s[1] += bf2f((unsigned short)(v.x >> 16));
          s[2] += bf2f((unsigned short)(v.y & 0xFFFF)); s[3] += bf2f((unsigned short)(v.y >> 16));
          s[4] += bf2f((unsigned short)(v.z & 0xFFFF)); s[5] += bf2f((unsigned short)(v.z >> 16));
          s[6] += bf2f((unsigned short)(v.w & 0xFFFF)); s[7] += bf2f((unsigned short)(v.w >> 16));
        }
        uint4 o;
        o.x = (unsigned)f2bf(s[0]*0.125f) | ((unsigned)f2bf(s[1]*0.125f) << 16);
        o.y = (unsigned)f2bf(s[2]*0.125f) | ((unsigned)f2bf(s[3]*0.125f) << 16);
        o.z = (unsigned)f2bf(s[4]*0.125f) | ((unsigned)f2bf(s[5]*0.125f) << 16);
        o.w = (unsigned)f2bf(s[6]*0.125f) | ((unsigned)f2bf(s[7]*0.125f) << 16);
        *(uint4*)&sA[r][qp] = o;
      } else {
        *(uint4*)&sA[r][qp] = *(const uint4*)&A[(size_t)(m0 + r) * NC + k0 + q * 8];
      }
      *(uint4*)&sB[r][qp] = *(const uint4*)&Wt[(size_t)(n0 + r) * NC + k0 + q * 8];
    }
    __syncthreads();
#pragma unroll
    for (int ks = 0; ks < 2; ++ks) {
      int qr = ks * 4 + (lane >> 4);
      bf8 a[4], b[2];
#pragma unroll
      for (int mf = 0; mf < 4; ++mf) {
        int rr = wm*64 + mf*16 + (lane & 15);
        a[mf] = *(const bf8*)&sA[rr][(qr ^ ((rr >> 1) & 7)) * 8];
      }
#pragma unroll
      for (int nf = 0; nf < 2; ++nf) {
        int rr = wn*32 + nf*16 + (lane & 15);
        b[nf] = *(const bf8*)&sB[rr][(qr ^ ((rr >> 1) & 7)) * 8];
      }
#pragma unroll
      for (int nf = 0; nf < 2; ++nf)
#pragma unroll
        for (int mf = 0; mf < 4; ++mf)
          acc[mf][nf] = __builtin_amdgcn_mfma_f32_16x16x32_bf16(a[mf], b[nf], acc[mf][nf], 0, 0, 0);
    }
    __syncthreads();
  }
#pragma unroll
  for (int nf = 0; nf < 2; ++nf) {
    int n = n0 + wn*32 + nf*16 + (lane & 15);
    float bi = bias[n];
    float s1 = 0.f, s2 = 0.f;
#pragma unroll
    for (int mf = 0; mf < 4; ++mf) {
#pragma unroll
      for (int r = 0; r < 4; ++r) {
        int m = m0 + wm*64 + mf*16 + (lane >> 4)*4 + r;
        float v = acc[mf][nf][r] + bi;
        if (OUTF32) ((float*)outp)[(size_t)m * NC + n] = v;
        else ((unsigned short*)outp)[(size_t)m * NC + n] = f2bf(v);
        if (BNS) { s1 += v; s2 = fmaf(v, v, s2); }
      }
    }
    if (BNS) {
      s1 += __shfl_xor(s1, 16); s1 += __shfl_xor(s1, 32);
      s2 += __shfl_xor(s2, 16); s2 += __shfl_xor(s2, 32);
      if (lane < 16) {
        atomicAdd(&bnsum[n], s1);
        atomicAdd(&bnsum[NC + n], s2);
      }
    }
  }
}

// ---------- 11. node scatter (bf16): relu(1/8 sum_{e∋n} xp[b,e,:]) (+bf16 residual) ----------
template<int MODE>
__global__ __launch_bounds__(256) void scatter_kernel(const unsigned short* __restrict__ xp,
                                                      const int* __restrict__ offsets,
                                                      const int* __restrict__ edgelist,
                                                      const unsigned short* __restrict__ res,
                                                      unsigned short* __restrict__ outb) {
  int b = blockIdx.y;
  int n = blockIdx.x * 4 + (threadIdx.x >> 6);
  int lane = threadIdx.x & 63;
  int s0i = offsets[n], s1i = offsets[n + 1];
  float s0 = 0, s1 = 0, s2 = 0, s3 = 0;
  for (int j = s0i; j < s1i; ++j) {
    int e = edgelist[j];
    uint2 v = *(const uint2*)&xp[((size_t)((b << 12) + e)) * NC + lane * 4];
    s0 += bf2f((unsigned short)(v.x & 0xFFFF)); s1 += bf2f((unsigned short)(v.x >> 16));
    s2 += bf2f((unsigned short)(v.y & 0xFFFF)); s3 += bf2f((unsigned short)(v.y >> 16));
  }
  s0 = fmaxf(s0 * 0.125f, 0.f); s1 = fmaxf(s1 * 0.125f, 0.f);
  s2 = fmaxf(s2 * 0.125f, 0.f); s3 = fmaxf(s3 * 0.125f, 0.f);
  size_t o = ((size_t)((b << 12) + n)) * NC + lane * 4;
  if (MODE == 1) {
    uint2 v = *(const uint2*)&res[o];
    s0 += bf2f((unsigned short)(v.x & 0xFFFF)); s1 += bf2f((unsigned short)(v.x >> 16));
    s2 += bf2f((unsigned short)(v.y & 0xFFFF)); s3 += bf2f((unsigned short)(v.y >> 16));
  }
  uint2 ov;
  ov.x = (unsigned)f2bf(s0) | ((unsigned)f2bf(s1) << 16);
  ov.y = (unsigned)f2bf(s2) | ((unsigned)f2bf(s3) << 16);
  *(uint2*)&outb[o] = ov;
}

// ---------- 12. transpose + BN (inline stats->affine) + residual ----------
__global__ __launch_bounds__(256) void final_kernel(const float* __restrict__ y,
                                                    const float* __restrict__ feat,
                                                    const float* __restrict__ bnsum,
                                                    const float* __restrict__ gam,
                                                    const float* __restrict__ bet,
                                                    float* __restrict__ out) {
  __shared__ float tile[64][65];
  __shared__ float sa_[64], sb_[64];
  int n0 = blockIdx.x * 64;
  int c0 = blockIdx.y * 64;
  int b  = blockIdx.z;
  int tid = threadIdx.x;
  if (tid < 64) {
    const float invn = 1.f / (float)(NB * NN);
    int c = c0 + tid;
    float mean = bnsum[c] * invn;
    float var  = bnsum[NC + c] * invn - mean * mean;
    float a = gam[c] * rsqrtf(var + 1e-5f);
    sa_[tid] = a;
    sb_[tid] = bet[c] - mean * a;
  }
  int n_l = tid >> 2;
  int q   = tid & 3;
  const float4* y4 = (const float4*)y;
#pragma unroll
  for (int i = 0; i < 4; ++i) {
    int cl = q * 16 + i * 4;
    float4 v = y4[(size_t)(b * NN + n0 + n_l) * 64 + ((c0 + cl) >> 2)];
    tile[n_l][cl+0] = v.x; tile[n_l][cl+1] = v.y; tile[n_l][cl+2] = v.z; tile[n_l][cl+3] = v.w;
  }
  __syncthreads();
  int cl2 = tid >> 6;
  int nl2 = tid & 63;
#pragma unroll
  for (int p = 0; p < 16; ++p) {
    int ci = p * 4 + cl2;
    float a = sa_[ci], bb = sb_[ci];
    size_t o = (size_t)b * (NC * NN) + (size_t)(c0 + ci) * NN + n0 + nl2;
    out[o] = feat[o] + fmaf(a, tile[nl2][ci], bb);
  }
}

}  // namespace

extern "C" void kernel_launch(void* const* d_in, const int* in_sizes, int n_in,
                              void* d_out, int out_size, void* d_ws, size_t ws_size,
                              hipStream_t stream) {
  (void)in_sizes; (void)n_in; (void)out_size; (void)ws_size;
  const float* feat = (const float*)d_in[0];
  const float* t0w  = (const float*)d_in[1];
  const float* t0b  = (const float*)d_in[2];
  const float* p0w  = (const float*)d_in[3];
  const float* p0b  = (const float*)d_in[4];
  const float* t1w  = (const float*)d_in[5];
  const float* t1b  = (const float*)d_in[6];
  const float* p1w  = (const float*)d_in[7];
  const float* p1b  = (const float*)d_in[8];
  const float* pw   = (const float*)d_in[9];
  const float* pb   = (const float*)d_in[10];
  const float* gam  = (const float*)d_in[11];
  const float* bet  = (const float*)d_in[12];
  float* out = (float*)d_out;

  // workspace layout (~77 MiB)
  char* ws = (char*)d_ws;
  float*          y   = (float*)ws;                          // 16 MiB fp32 [B*N][C]
  unsigned short* xin = (unsigned short*)(ws + (16u << 20)); // 8 MiB each
  unsigned short* xt  = (unsigned short*)(ws + (24u << 20));
  unsigned short* xp  = (unsigned short*)(ws + (40u << 20));
  unsigned short* x1  = (unsigned short*)(ws + (48u << 20));
  unsigned short* x2  = (unsigned short*)(ws + (56u << 20));
  unsigned short* Xhi = (unsigned short*)(ws + (64u << 20)); // 2 MiB
  unsigned short* Xlo = (unsigned short*)(ws + (66u << 20)); // 2 MiB
  ull*            cand = (ull*)(ws + (68u << 20));           // 8 MiB (4096*256 ull)
  char* sm = ws + (76u << 20);
  unsigned short* Wt  = (unsigned short*)sm;                 // 5*128 KiB
  int*   idx8     = (int*)(sm + 655360);                     // 128 KiB
  int*   counts   = (int*)(sm + 786432);                     // 16 KiB
  int*   offsets  = (int*)(sm + 802816);                     // 16 KiB + 4
  int*   cursor   = (int*)(sm + 819456);                     // 16 KiB
  int*   edgelist = (int*)(sm + 835840);                     // 128 KiB
  float* inv      = (float*)(sm + 966912);                   // 16 KiB
  float* bnsum    = (float*)(sm + 983296);                   // 2 KiB

  norm_kernel<<<NN / 256, 256, 0, stream>>>(feat, inv, counts, bnsum);
  xpose_split_kernel<<<dim3(64, 4), 256, 0, stream>>>(feat, inv, Xhi, Xlo);
  wcvt_kernel<<<dim3(4, 4, 5), 256, 0, stream>>>(t0w, p0w, t1w, p1w, pw, Wt);
  feat2bf_kernel<<<dim3(64, 4, 4), 256, 0, stream>>>(feat, xin);

  // symmetric fused sim + per-tile top-8 (upper triangle only)
  simtop_kernel<<<528, 512, 0, stream>>>(Xhi, Xlo, cand);
  merge_kernel<<<128, 256, 0, stream>>>(cand, idx8, counts);
  scan_kernel<<<1, 256, 0, stream>>>(counts, offsets, cursor);
  fill_kernel<<<128, 256, 0, stream>>>(idx8, cursor, edgelist);

  // layer 0: theta -> (fused gather+phi) -> scatter
  gemm_bf16_kernel<0,0,0><<<dim3(2, 128), 512, 0, stream>>>(xin, Wt + 0*65536, t0b, xt, nullptr, nullptr);
  gemm_bf16_kernel<0,0,1><<<dim3(2, 128), 512, 0, stream>>>(xt,  Wt + 1*65536, p0b, xp, nullptr, idx8);
  scatter_kernel<0><<<dim3(1024, 4), 256, 0, stream>>>(xp, offsets, edgelist, nullptr, x1);
  // layer 1
  gemm_bf16_kernel<0,0,0><<<dim3(2, 128), 512, 0, stream>>>(x1, Wt + 2*65536, t1b, xt, nullptr, nullptr);
  gemm_bf16_kernel<0,0,1><<<dim3(2, 128), 512, 0, stream>>>(xt, Wt + 3*65536, p1b, xp, nullptr, idx8);
  scatter_kernel<1><<<dim3(1024, 4), 256, 0, stream>>>(xp, offsets, edgelist, x1, x2);
  // proj (fp32 out) + fused BN stats
  gemm_bf16_kernel<1,1,0><<<dim3(2, 128), 512, 0, stream>>>(x2, Wt + 4*65536, pb, y, bnsum, nullptr);

  final_kernel<<<dim3(64, 4, 4), 256, 0, stream>>>(y, feat, bnsum, gam, bet, out);
}